// Round 1
// baseline (2589.815 us; speedup 1.0000x reference)
//
#include <hip/hip_runtime.h>

#define SEQ     2048
#define DMODEL  2048
#define DINNER  4096
#define DXB     512
#define DSTATE  16
#define DTRANK  128
#define ZXBC_N  9216   // 2*DXB + 2*DINNER
#define NGROUP  256    // NUM_C_HEAD

// zxbc row layout: [ z:0..4096 | x:4096..4608 | B:4608..5120 | C:5120..9216 ]
#define OFF_Z 0
#define OFF_X 4096
#define OFF_B 4608
#define OFF_C 5120

__device__ __forceinline__ float softplus_f(float x) {
    return x > 0.f ? x + log1pf(expf(-x)) : log1pf(expf(x));
}
__device__ __forceinline__ float silu_f(float x) {
    return x / (1.f + __expf(-x));
}

// C[M,N] = A[M,K] * B[N,K]^T   (both row-major, K contiguous)
// EPI==1: C = softplus(C + bias[col])
template<int EPI>
__global__ __launch_bounds__(256) void gemm_nt(const float* __restrict__ A,
                                               const float* __restrict__ B,
                                               float* __restrict__ C,
                                               int M, int N, int K,
                                               const float* __restrict__ bias) {
    __shared__ float As[16][64];
    __shared__ float Bs[16][64];
    const int tid  = threadIdx.x;
    const int row0 = blockIdx.y * 64;
    const int col0 = blockIdx.x * 64;
    const int tx = tid & 15, ty = tid >> 4;
    const int lr = tid >> 2;          // 0..63 (row within tile)
    const int lk = (tid & 3) << 2;    // 0,4,8,12 (k offset)
    const float* Ap = A + (size_t)(row0 + lr) * K + lk;
    const float* Bp = B + (size_t)(col0 + lr) * K + lk;
    float acc[4][4] = {};
    for (int k0 = 0; k0 < K; k0 += 16) {
        const float4 av = *(const float4*)(Ap + k0);
        const float4 bv = *(const float4*)(Bp + k0);
        __syncthreads();
        As[lk+0][lr] = av.x; As[lk+1][lr] = av.y; As[lk+2][lr] = av.z; As[lk+3][lr] = av.w;
        Bs[lk+0][lr] = bv.x; Bs[lk+1][lr] = bv.y; Bs[lk+2][lr] = bv.z; Bs[lk+3][lr] = bv.w;
        __syncthreads();
        #pragma unroll
        for (int k = 0; k < 16; ++k) {
            const float4 a = *(const float4*)&As[k][ty << 2];
            const float4 b = *(const float4*)&Bs[k][tx << 2];
            const float ar[4] = {a.x, a.y, a.z, a.w};
            const float br[4] = {b.x, b.y, b.z, b.w};
            #pragma unroll
            for (int i = 0; i < 4; ++i)
                #pragma unroll
                for (int j = 0; j < 4; ++j)
                    acc[i][j] = fmaf(ar[i], br[j], acc[i][j]);
        }
    }
    #pragma unroll
    for (int i = 0; i < 4; ++i) {
        const int row = row0 + (ty << 2) + i;
        float4 v;
        float* vp = &v.x;
        #pragma unroll
        for (int j = 0; j < 4; ++j) {
            float t = acc[i][j];
            if (EPI == 1) {
                t += bias[col0 + (tx << 2) + j];
                t = softplus_f(t);
            }
            vp[j] = t;
        }
        *(float4*)&C[(size_t)row * N + col0 + (tx << 2)] = v;
    }
}

// depthwise causal conv over time + silu -> u[t][c]
__global__ __launch_bounds__(256) void conv_silu_kernel(const float* __restrict__ zxbc,
                                                        const float* __restrict__ conv_w,
                                                        const float* __restrict__ conv_b,
                                                        float* __restrict__ u) {
    const int idx = blockIdx.x * 256 + threadIdx.x;   // t*4096 + c
    const int c = idx & (DINNER - 1);
    const int t = idx >> 12;
    // channel c -> x column: head g=c>>4, source xb-head g>>3, state c&15
    const int xcol = ((c >> 7) << 4) | (c & 15);
    const float* xp = zxbc + OFF_X + xcol;
    const float4 w4 = *(const float4*)(conv_w + c * 4);
    const float wk[4] = {w4.x, w4.y, w4.z, w4.w};
    float acc = conv_b[c];
    if (t >= 3) {
        acc = fmaf(wk[0], xp[(size_t)(t-3) * ZXBC_N], acc);
        acc = fmaf(wk[1], xp[(size_t)(t-2) * ZXBC_N], acc);
        acc = fmaf(wk[2], xp[(size_t)(t-1) * ZXBC_N], acc);
        acc = fmaf(wk[3], xp[(size_t)(t  ) * ZXBC_N], acc);
    } else {
        #pragma unroll
        for (int k = 0; k < 4; ++k) {
            const int tt = t - 3 + k;
            if (tt >= 0) acc = fmaf(wk[k], xp[(size_t)tt * ZXBC_N], acc);
        }
    }
    u[idx] = silu_f(acc);
}

// selective scan: one block per head g (16 p * 16 n threads); state in regs.
// writes ypre[t][c] = (y + u*D) * silu(z)
__global__ __launch_bounds__(256) void scan_kernel(const float* __restrict__ zxbc,
                                                   const float* __restrict__ delta,
                                                   const float* __restrict__ u,
                                                   const float* __restrict__ A_log,
                                                   const float* __restrict__ Dvec,
                                                   float* __restrict__ ypre) {
    const int g   = blockIdx.x;      // 0..255
    const int tid = threadIdx.x;
    const int n = tid & 15, p = tid >> 4;
    const int c = g * 16 + p;        // channel
    const float A  = -expf(A_log[c * 16 + n]);
    const float Dv = Dvec[c];
    const float* Bp = zxbc + OFF_B + ((g >> 3) << 4) + n;
    const float* Cp = zxbc + OFF_C + (g << 4) + n;
    const float* zp = zxbc + OFF_Z + c;
    float h = 0.f;
    // prefetch t=0
    float d_t = delta[c];
    float u_t = u[c];
    float B_t = Bp[0];
    float C_t = Cp[0];
    float z_t = zp[0];
    for (int t = 0; t < SEQ; ++t) {
        float dn = 0.f, un = 0.f, Bn = 0.f, Cn = 0.f, zn = 0.f;
        if (t < SEQ - 1) {
            const size_t r = (size_t)(t + 1);
            dn = delta[r * DINNER + c];
            un = u[r * DINNER + c];
            Bn = Bp[r * ZXBC_N];
            Cn = Cp[r * ZXBC_N];
            zn = zp[r * ZXBC_N];
        }
        const float dA = __expf(d_t * A);
        h = fmaf(h, dA, d_t * u_t * B_t);
        float yp = h * C_t;
        yp += __shfl_xor(yp, 1);
        yp += __shfl_xor(yp, 2);
        yp += __shfl_xor(yp, 4);
        yp += __shfl_xor(yp, 8);
        if (n == 0) {
            const float yv = fmaf(u_t, Dv, yp) * silu_f(z_t);
            ypre[(size_t)t * DINNER + c] = yv;
        }
        d_t = dn; u_t = un; B_t = Bn; C_t = Cn; z_t = zn;
    }
}

extern "C" void kernel_launch(void* const* d_in, const int* in_sizes, int n_in,
                              void* d_out, int out_size, void* d_ws, size_t ws_size,
                              hipStream_t stream) {
    const float* hidden       = (const float*)d_in[0];
    const float* in_proj_w    = (const float*)d_in[1];
    const float* dt_in_proj_w = (const float*)d_in[2];
    const float* dt_proj_w    = (const float*)d_in[3];
    const float* dt_proj_b    = (const float*)d_in[4];
    const float* conv_w       = (const float*)d_in[5];
    const float* conv_b       = (const float*)d_in[6];
    const float* A_log        = (const float*)d_in[7];
    const float* Dvec         = (const float*)d_in[8];
    const float* out_proj_w   = (const float*)d_in[9];
    float* out = (float*)d_out;

    float* ws    = (float*)d_ws;
    float* zxbc  = ws;                                   // 2048*9216
    float* t1    = zxbc  + (size_t)SEQ * ZXBC_N;         // 2048*128
    float* delta = t1    + (size_t)SEQ * DTRANK;         // 2048*4096
    float* u     = delta + (size_t)SEQ * DINNER;         // 2048*4096
    float* ypre  = u     + (size_t)SEQ * DINNER;         // 2048*4096

    // zxbc = hidden @ in_proj_w^T
    gemm_nt<0><<<dim3(ZXBC_N / 64, SEQ / 64), 256, 0, stream>>>(
        hidden, in_proj_w, zxbc, SEQ, ZXBC_N, DMODEL, nullptr);
    // t1 = hidden @ dt_in_proj_w^T
    gemm_nt<0><<<dim3(DTRANK / 64, SEQ / 64), 256, 0, stream>>>(
        hidden, dt_in_proj_w, t1, SEQ, DTRANK, DMODEL, nullptr);
    // delta = softplus(t1 @ dt_proj_w^T + dt_proj_b)
    gemm_nt<1><<<dim3(DINNER / 64, SEQ / 64), 256, 0, stream>>>(
        t1, dt_proj_w, delta, SEQ, DINNER, DTRANK, dt_proj_b);
    // u = silu(depthwise_causal_conv(x-repeat) + conv_b)
    conv_silu_kernel<<<(SEQ * DINNER) / 256, 256, 0, stream>>>(zxbc, conv_w, conv_b, u);
    // sequential selective scan -> ypre
    scan_kernel<<<NGROUP, 256, 0, stream>>>(zxbc, delta, u, A_log, Dvec, ypre);
    // out = ypre @ out_proj_w^T
    gemm_nt<0><<<dim3(DMODEL / 64, SEQ / 64), 256, 0, stream>>>(
        ypre, out_proj_w, out, SEQ, DMODEL, DINNER, nullptr);
}

// Round 2
// 938.219 us; speedup vs baseline: 2.7604x; 2.7604x over previous
//
#include <hip/hip_runtime.h>
#include <hip/hip_bf16.h>

#define SEQ     2048
#define DMODEL  2048
#define DINNER  4096
#define DXB     512
#define DSTATE  16
#define DTRANK  128
#define ZXBC_N  9216   // 2*DXB + 2*DINNER
#define NGROUP  256    // NUM_C_HEAD
#define TCH     128    // scan time-chunk staged in LDS

// zxbc row layout: [ z:0..4096 | x:4096..4608 | B:4608..5120 | C:5120..9216 ]
#define OFF_Z 0
#define OFF_X 4096
#define OFF_B 4608
#define OFF_C 5120

typedef __attribute__((ext_vector_type(8))) short short8;
typedef __attribute__((ext_vector_type(4))) float f32x4;

__device__ __forceinline__ float softplus_f(float x) {
    return x > 0.f ? x + log1pf(expf(-x)) : log1pf(expf(x));
}
__device__ __forceinline__ float silu_f(float x) {
    return x / (1.f + __expf(-x));
}
__device__ __forceinline__ ushort f2bf(float f) {
    union { float f; unsigned u; } v; v.f = f;
    unsigned r = v.u + 0x7fffu + ((v.u >> 16) & 1u);   // RNE
    return (ushort)(r >> 16);
}

__global__ __launch_bounds__(256) void f32_to_bf16(const float* __restrict__ in,
                                                   ushort* __restrict__ out, int n4) {
    int i = blockIdx.x * 256 + threadIdx.x;
    if (i < n4) {
        float4 v = ((const float4*)in)[i];
        ushort4 o;
        o.x = f2bf(v.x); o.y = f2bf(v.y); o.z = f2bf(v.z); o.w = f2bf(v.w);
        ((ushort4*)out)[i] = o;
    }
}

#define GLOAD16(gp, lp) __builtin_amdgcn_global_load_lds( \
    (const __attribute__((address_space(1))) void*)(gp), \
    (__attribute__((address_space(3))) void*)(lp), 16, 0, 0)

// C[M,N] = A[M,K] (bf16, row-major) * B[N,K]^T (bf16, row-major), fp32 accumulate.
// EPI 0: f32 out. EPI 1: f32 out = softplus(acc + bias[col]). EPI 2: bf16 out.
// m97 structure: 128x128 tile, BK=32, 4 waves (2x2 of 64x64), 16x16x32 MFMA,
// global_load_lds width=16 staging, 1D grid with XCD-aware swizzle.
template<int EPI>
__global__ __launch_bounds__(256) void gemm_bt_bf16(const ushort* __restrict__ A,
                                                    const ushort* __restrict__ B,
                                                    void* __restrict__ Cout,
                                                    const float* __restrict__ bias,
                                                    int M, int N, int K) {
    __shared__ ushort As[128 * 32];
    __shared__ ushort Bs[128 * 32];
    const int nbx = N >> 7;
    const int nwg = gridDim.x;
    int lin = blockIdx.x;
    if ((nwg & 7) == 0) lin = (lin & 7) * (nwg >> 3) + (lin >> 3);  // XCD swizzle
    const int by = lin / nbx;
    const int bx = lin - by * nbx;
    const int row0 = by << 7, col0 = bx << 7;

    const int tid  = threadIdx.x;
    const int w    = tid >> 6;
    const int lane = tid & 63;

    // staging: wave w fills rows [32w, 32w+32) of each LDS tile; two 1KB chunks.
    const int srow = (w << 5) + (lane >> 2);
    const int skb  = (lane & 3) << 3;                 // bf16 elem offset within row
    const ushort* ag = A + (size_t)(row0 + srow) * K + skb;
    const ushort* bg = B + (size_t)(col0 + srow) * K + skb;
    ushort* al0 = As + ((w << 5) +  0) * 32;
    ushort* al1 = As + ((w << 5) + 16) * 32;
    ushort* bl0 = Bs + ((w << 5) +  0) * 32;
    ushort* bl1 = Bs + ((w << 5) + 16) * 32;

    // compute: wave (wm,wn) owns a 64x64 quadrant; 4x4 fragments of 16x16.
    const int wm = (w >> 1) << 6;
    const int wn = (w & 1) << 6;
    const int fr = lane & 15;
    const int ko = (lane >> 4) << 3;

    f32x4 acc[4][4] = {};
    for (int k0 = 0; k0 < K; k0 += 32) {
        __syncthreads();
        GLOAD16(ag,                  al0);
        GLOAD16(ag + (size_t)16 * K, al1);
        GLOAD16(bg,                  bl0);
        GLOAD16(bg + (size_t)16 * K, bl1);
        ag += 32; bg += 32;
        __syncthreads();   // drains vmcnt (global_load_lds) before reads
        short8 af[4], bf[4];
        #pragma unroll
        for (int i = 0; i < 4; ++i)
            af[i] = *(const short8*)(As + (wm + i * 16 + fr) * 32 + ko);
        #pragma unroll
        for (int j = 0; j < 4; ++j)
            bf[j] = *(const short8*)(Bs + (wn + j * 16 + fr) * 32 + ko);
        #pragma unroll
        for (int i = 0; i < 4; ++i)
            #pragma unroll
            for (int j = 0; j < 4; ++j)
                acc[i][j] = __builtin_amdgcn_mfma_f32_16x16x32_bf16(af[i], bf[j], acc[i][j], 0, 0, 0);
    }

    // C/D layout: col = lane&15, row = (lane>>4)*4 + r  [m89-verified]
    const int orow = row0 + wm + ((lane >> 4) << 2);
    const int ocol = col0 + wn + fr;
    #pragma unroll
    for (int i = 0; i < 4; ++i) {
        #pragma unroll
        for (int r = 0; r < 4; ++r) {
            const int row = orow + i * 16 + r;
            #pragma unroll
            for (int j = 0; j < 4; ++j) {
                const int col = ocol + j * 16;
                float v = acc[i][j][r];
                if (EPI == 1) v = softplus_f(v + bias[col]);
                if (EPI == 2) ((ushort*)Cout)[(size_t)row * N + col] = f2bf(v);
                else          ((float*)Cout)[(size_t)row * N + col] = v;
            }
        }
    }
}

// Selective scan, fused depthwise causal conv + silu + gating.
// One block per c-head g: threads (p=tid>>4 [channel-in-head], n=tid&15 [state]).
// Inputs staged in LDS 128 timesteps at a time with register double-buffering.
// Writes ypre[t][c] = (y + u*D) * silu(z) as bf16.
__global__ __launch_bounds__(256) void scan_fused(const float* __restrict__ zxbc,
                                                  const float* __restrict__ delta,
                                                  const float* __restrict__ conv_w,
                                                  const float* __restrict__ conv_b,
                                                  const float* __restrict__ A_log,
                                                  const float* __restrict__ Dvec,
                                                  ushort* __restrict__ ypre) {
    __shared__ float sd[TCH][16], sz[TCH][16], sB[TCH][16], sC[TCH][16], sx[TCH][16];
    const int g   = blockIdx.x;
    const int tid = threadIdx.x;
    const int p = tid >> 4, n = tid & 15;
    const int c = (g << 4) + p;
    const float Av = -expf(A_log[(c << 4) + n]);
    const float Dv = Dvec[c];
    const float4 w4 = *(const float4*)(conv_w + c * 4);
    const float cb = conv_b[c];

    // staging mapping: thread -> (row r0 / r0+64, 4-col group q)
    const int r0 = tid >> 2;
    const int q  = (tid & 3) << 2;
    const float* pd = delta + (g << 4) + q;
    const float* pz = zxbc + OFF_Z + (g << 4) + q;
    const float* pB = zxbc + OFF_B + ((g >> 3) << 4) + q;
    const float* pC = zxbc + OFF_C + (g << 4) + q;
    const float* px = zxbc + OFF_X + ((g >> 3) << 4) + q;

    float4 rd0, rd1, rz0, rz1, rB0, rB1, rC0, rC1, rx0, rx1;
    {
        const size_t ta = (size_t)r0, tb = (size_t)(r0 + 64);
        rd0 = *(const float4*)(pd + ta * DINNER);  rd1 = *(const float4*)(pd + tb * DINNER);
        rz0 = *(const float4*)(pz + ta * ZXBC_N);  rz1 = *(const float4*)(pz + tb * ZXBC_N);
        rB0 = *(const float4*)(pB + ta * ZXBC_N);  rB1 = *(const float4*)(pB + tb * ZXBC_N);
        rC0 = *(const float4*)(pC + ta * ZXBC_N);  rC1 = *(const float4*)(pC + tb * ZXBC_N);
        rx0 = *(const float4*)(px + ta * ZXBC_N);  rx1 = *(const float4*)(px + tb * ZXBC_N);
    }

    float h = 0.f, xm1 = 0.f, xm2 = 0.f, xm3 = 0.f;
    for (int ch = 0; ch < SEQ / TCH; ++ch) {
        __syncthreads();   // previous chunk's compute done (no-op on first iter)
        *(float4*)&sd[r0][q] = rd0;  *(float4*)&sd[r0 + 64][q] = rd1;
        *(float4*)&sz[r0][q] = rz0;  *(float4*)&sz[r0 + 64][q] = rz1;
        *(float4*)&sB[r0][q] = rB0;  *(float4*)&sB[r0 + 64][q] = rB1;
        *(float4*)&sC[r0][q] = rC0;  *(float4*)&sC[r0 + 64][q] = rC1;
        *(float4*)&sx[r0][q] = rx0;  *(float4*)&sx[r0 + 64][q] = rx1;
        __syncthreads();
        if (ch + 1 < SEQ / TCH) {   // prefetch next chunk; waited at next LDS-write
            const size_t ta = (size_t)((ch + 1) * TCH + r0), tb = ta + 64;
            rd0 = *(const float4*)(pd + ta * DINNER);  rd1 = *(const float4*)(pd + tb * DINNER);
            rz0 = *(const float4*)(pz + ta * ZXBC_N);  rz1 = *(const float4*)(pz + tb * ZXBC_N);
            rB0 = *(const float4*)(pB + ta * ZXBC_N);  rB1 = *(const float4*)(pB + tb * ZXBC_N);
            rC0 = *(const float4*)(pC + ta * ZXBC_N);  rC1 = *(const float4*)(pC + tb * ZXBC_N);
            rx0 = *(const float4*)(px + ta * ZXBC_N);  rx1 = *(const float4*)(px + tb * ZXBC_N);
        }
        const int tbase = ch * TCH;
        #pragma unroll 4
        for (int tl = 0; tl < TCH; ++tl) {
            const float d  = sd[tl][p];
            const float z  = sz[tl][p];
            const float xt = sx[tl][p];
            const float Bv = sB[tl][n];
            const float Cv = sC[tl][n];
            float u = cb;
            u = fmaf(w4.x, xm3, u); u = fmaf(w4.y, xm2, u);
            u = fmaf(w4.z, xm1, u); u = fmaf(w4.w, xt, u);
            u = silu_f(u);
            xm3 = xm2; xm2 = xm1; xm1 = xt;
            const float dA = __expf(d * Av);
            h = fmaf(h, dA, d * u * Bv);
            float yp = h * Cv;
            yp += __shfl_xor(yp, 1);
            yp += __shfl_xor(yp, 2);
            yp += __shfl_xor(yp, 4);
            yp += __shfl_xor(yp, 8);
            if (n == 0) {
                const float yv = fmaf(u, Dv, yp) * silu_f(z);
                ypre[(size_t)(tbase + tl) * DINNER + c] = f2bf(yv);
            }
        }
    }
}

extern "C" void kernel_launch(void* const* d_in, const int* in_sizes, int n_in,
                              void* d_out, int out_size, void* d_ws, size_t ws_size,
                              hipStream_t stream) {
    const float* hidden       = (const float*)d_in[0];
    const float* in_proj_w    = (const float*)d_in[1];
    const float* dt_in_proj_w = (const float*)d_in[2];
    const float* dt_proj_w    = (const float*)d_in[3];
    const float* dt_proj_b    = (const float*)d_in[4];
    const float* conv_w       = (const float*)d_in[5];
    const float* conv_b       = (const float*)d_in[6];
    const float* A_log        = (const float*)d_in[7];
    const float* Dvec         = (const float*)d_in[8];
    const float* out_proj_w   = (const float*)d_in[9];

    // workspace layout (bytes); wbig is in_proj(bf16) then reused for out_proj(bf16)
    char* wsb = (char*)d_ws;
    float*  zxbc  = (float*) (wsb + 0ull);            // 2048*9216*4  = 75,497,472
    float*  delta = (float*) (wsb + 75497472ull);     // 2048*4096*4  = 33,554,432
    ushort* ypre  = (ushort*)(wsb + 109051904ull);    // 2048*4096*2  = 16,777,216
    ushort* hb    = (ushort*)(wsb + 125829120ull);    // 2048*2048*2  =  8,388,608
    ushort* t1b   = (ushort*)(wsb + 134217728ull);    // 2048*128*2   =    524,288
    ushort* wdtib = (ushort*)(wsb + 134742016ull);    // 128*2048*2   =    524,288
    ushort* wdtpb = (ushort*)(wsb + 135266304ull);    // 4096*128*2   =  1,048,576
    ushort* wbig  = (ushort*)(wsb + 136314880ull);    // 9216*2048*2  = 37,748,736

    f32_to_bf16<<<4096,  256, 0, stream>>>(hidden,       hb,    1048576);
    f32_to_bf16<<<18432, 256, 0, stream>>>(in_proj_w,    wbig,  4718592);
    f32_to_bf16<<<256,   256, 0, stream>>>(dt_in_proj_w, wdtib, 65536);
    f32_to_bf16<<<512,   256, 0, stream>>>(dt_proj_w,    wdtpb, 131072);

    // zxbc = hidden @ in_proj_w^T  (fp32 out, consumed by scan staging)
    gemm_bt_bf16<0><<<1152, 256, 0, stream>>>(hb, wbig, zxbc, nullptr, SEQ, ZXBC_N, DMODEL);
    // wbig now free -> out_proj bf16
    f32_to_bf16<<<8192, 256, 0, stream>>>(out_proj_w, wbig, 2097152);
    // t1 = hidden @ dt_in_proj_w^T  (bf16 out)
    gemm_bt_bf16<2><<<16, 256, 0, stream>>>(hb, wdtib, t1b, nullptr, SEQ, DTRANK, DMODEL);
    // delta = softplus(t1 @ dt_proj_w^T + dt_proj_b)  (fp32 out)
    gemm_bt_bf16<1><<<512, 256, 0, stream>>>(t1b, wdtpb, delta, dt_proj_b, SEQ, DINNER, DTRANK);
    // fused conv+silu+scan+gate -> ypre (bf16)
    scan_fused<<<NGROUP, 256, 0, stream>>>(zxbc, delta, conv_w, conv_b, A_log, Dvec, ypre);
    // out = ypre @ out_proj_w^T  (fp32 out)
    gemm_bt_bf16<0><<<256, 256, 0, stream>>>(ypre, wbig, (float*)d_out, nullptr, SEQ, DMODEL, DINNER);
}

// Round 3
// 630.449 us; speedup vs baseline: 4.1079x; 1.4882x over previous
//
#include <hip/hip_runtime.h>
#include <hip/hip_bf16.h>

#define SEQ     2048
#define DMODEL  2048
#define DINNER  4096
#define DXB     512
#define DSTATE  16
#define DTRANK  128
#define ZXBC_N  9216   // 2*DXB + 2*DINNER
#define NGROUP  256    // NUM_C_HEAD
#define NCH     32     // time chunks
#define TC      64     // steps per chunk

// zxbc row layout: [ z:0..4096 | x:4096..4608 | B:4608..5120 | C:5120..9216 ]
#define OFF_Z 0
#define OFF_X 4096
#define OFF_B 4608
#define OFF_C 5120

typedef __attribute__((ext_vector_type(8))) short short8;
typedef __attribute__((ext_vector_type(4))) float f32x4;

__device__ __forceinline__ float softplus_f(float x) {
    return x > 0.f ? x + log1pf(expf(-x)) : log1pf(expf(x));
}
__device__ __forceinline__ float silu_f(float x) {
    return x / (1.f + __expf(-x));
}
__device__ __forceinline__ ushort f2bf(float f) {
    union { float f; unsigned u; } v; v.f = f;
    unsigned r = v.u + 0x7fffu + ((v.u >> 16) & 1u);   // RNE
    return (ushort)(r >> 16);
}

__global__ __launch_bounds__(256) void f32_to_bf16(const float* __restrict__ in,
                                                   ushort* __restrict__ out, int n4) {
    int i = blockIdx.x * 256 + threadIdx.x;
    if (i < n4) {
        float4 v = ((const float4*)in)[i];
        ushort4 o;
        o.x = f2bf(v.x); o.y = f2bf(v.y); o.z = f2bf(v.z); o.w = f2bf(v.w);
        ((ushort4*)out)[i] = o;
    }
}

#define GLOAD16(gp, lp) __builtin_amdgcn_global_load_lds( \
    (const __attribute__((address_space(1))) void*)(gp), \
    (__attribute__((address_space(3))) void*)(lp), 16, 0, 0)

// C[M,N] = A[M,K] (bf16, row-major) * B[N,K]^T (bf16, row-major), fp32 accumulate.
// EPI 0: f32 out. EPI 1: f32 out = softplus(acc + bias[col]). EPI 2: bf16 out.
template<int EPI>
__global__ __launch_bounds__(256) void gemm_bt_bf16(const ushort* __restrict__ A,
                                                    const ushort* __restrict__ B,
                                                    void* __restrict__ Cout,
                                                    const float* __restrict__ bias,
                                                    int M, int N, int K) {
    __shared__ ushort As[128 * 32];
    __shared__ ushort Bs[128 * 32];
    const int nbx = N >> 7;
    const int nwg = gridDim.x;
    int lin = blockIdx.x;
    if ((nwg & 7) == 0) lin = (lin & 7) * (nwg >> 3) + (lin >> 3);  // XCD swizzle
    const int by = lin / nbx;
    const int bx = lin - by * nbx;
    const int row0 = by << 7, col0 = bx << 7;

    const int tid  = threadIdx.x;
    const int w    = tid >> 6;
    const int lane = tid & 63;

    const int srow = (w << 5) + (lane >> 2);
    const int skb  = (lane & 3) << 3;
    const ushort* ag = A + (size_t)(row0 + srow) * K + skb;
    const ushort* bg = B + (size_t)(col0 + srow) * K + skb;
    ushort* al0 = As + ((w << 5) +  0) * 32;
    ushort* al1 = As + ((w << 5) + 16) * 32;
    ushort* bl0 = Bs + ((w << 5) +  0) * 32;
    ushort* bl1 = Bs + ((w << 5) + 16) * 32;

    const int wm = (w >> 1) << 6;
    const int wn = (w & 1) << 6;
    const int fr = lane & 15;
    const int ko = (lane >> 4) << 3;

    f32x4 acc[4][4] = {};
    for (int k0 = 0; k0 < K; k0 += 32) {
        __syncthreads();
        GLOAD16(ag,                  al0);
        GLOAD16(ag + (size_t)16 * K, al1);
        GLOAD16(bg,                  bl0);
        GLOAD16(bg + (size_t)16 * K, bl1);
        ag += 32; bg += 32;
        __syncthreads();
        short8 af[4], bf[4];
        #pragma unroll
        for (int i = 0; i < 4; ++i)
            af[i] = *(const short8*)(As + (wm + i * 16 + fr) * 32 + ko);
        #pragma unroll
        for (int j = 0; j < 4; ++j)
            bf[j] = *(const short8*)(Bs + (wn + j * 16 + fr) * 32 + ko);
        #pragma unroll
        for (int i = 0; i < 4; ++i)
            #pragma unroll
            for (int j = 0; j < 4; ++j)
                acc[i][j] = __builtin_amdgcn_mfma_f32_16x16x32_bf16(af[i], bf[j], acc[i][j], 0, 0, 0);
    }

    const int orow = row0 + wm + ((lane >> 4) << 2);
    const int ocol = col0 + wn + fr;
    #pragma unroll
    for (int i = 0; i < 4; ++i) {
        #pragma unroll
        for (int r = 0; r < 4; ++r) {
            const int row = orow + i * 16 + r;
            #pragma unroll
            for (int j = 0; j < 4; ++j) {
                const int col = ocol + j * 16;
                float v = acc[i][j][r];
                if (EPI == 1) v = softplus_f(v + bias[col]);
                if (EPI == 2) ((ushort*)Cout)[(size_t)row * N + col] = f2bf(v);
                else          ((float*)Cout)[(size_t)row * N + col] = v;
            }
        }
    }
}

// ---- chunked selective scan ----
// Pass 1: per (head g, chunk ch): local scan from h=0. Stores h_local_end per
// (c,n) and sum(delta) per c. No y computation -> recurrent chain is one fma.
__global__ __launch_bounds__(256) void scan_pass1(const float* __restrict__ zxbc,
                                                  const float* __restrict__ delta,
                                                  const float* __restrict__ conv_w,
                                                  const float* __restrict__ conv_b,
                                                  const float* __restrict__ A_log,
                                                  float* __restrict__ hend,
                                                  float* __restrict__ dsum) {
    __shared__ float sd[TC][16], sB[TC][16], sx[TC][16];
    const int g = blockIdx.x, ch = blockIdx.y;
    const int tid = threadIdx.x;
    const int p = tid >> 4, n = tid & 15;
    const int c = (g << 4) + p;
    const int t0 = ch * TC;
    const float Av = -expf(A_log[(c << 4) + n]);
    const float4 w4 = *(const float4*)(conv_w + c * 4);
    const float cb = conv_b[c];

    const int r = tid >> 2, q = (tid & 3) << 2;
    *(float4*)&sd[r][q] = *(const float4*)(delta + (size_t)(t0 + r) * DINNER + (g << 4) + q);
    *(float4*)&sB[r][q] = *(const float4*)(zxbc + (size_t)(t0 + r) * ZXBC_N + OFF_B + ((g >> 3) << 4) + q);
    *(float4*)&sx[r][q] = *(const float4*)(zxbc + (size_t)(t0 + r) * ZXBC_N + OFF_X + ((g >> 3) << 4) + q);

    // conv history from global (zeros for first chunk)
    const size_t xg = OFF_X + ((size_t)(g >> 3) << 4) + p;
    float xm3 = 0.f, xm2 = 0.f, xm1 = 0.f;
    if (ch > 0) {
        xm3 = zxbc[(size_t)(t0 - 3) * ZXBC_N + xg];
        xm2 = zxbc[(size_t)(t0 - 2) * ZXBC_N + xg];
        xm1 = zxbc[(size_t)(t0 - 1) * ZXBC_N + xg];
    }
    float h = 0.f, Dc = 0.f;
    __syncthreads();
    #pragma unroll 8
    for (int tl = 0; tl < TC; ++tl) {
        const float xt = sx[tl][p];
        const float d  = sd[tl][p];
        const float Bv = sB[tl][n];
        float u = cb;
        u = fmaf(w4.x, xm3, u); u = fmaf(w4.y, xm2, u);
        u = fmaf(w4.z, xm1, u); u = fmaf(w4.w, xt, u);
        u = silu_f(u);
        xm3 = xm2; xm2 = xm1; xm1 = xt;
        Dc += d;
        h = fmaf(h, __expf(d * Av), d * u * Bv);
    }
    hend[((size_t)ch * DINNER + c) * 16 + n] = h;
    if (n == 0) dsum[(size_t)ch * DINNER + c] = Dc;
}

// Pass 2 (tiny): sequential combine over chunks per state (c,n).
// Rewrites hend[ch] in place with h0[ch] (state at chunk start).
__global__ __launch_bounds__(256) void scan_mid(const float* __restrict__ A_log,
                                                float* __restrict__ hend,
                                                const float* __restrict__ dsum) {
    const int idx = blockIdx.x * 256 + threadIdx.x;   // 0..65535
    const int c = idx >> 4, n = idx & 15;
    const float Av = -expf(A_log[(c << 4) + n]);
    float h = 0.f;
    #pragma unroll
    for (int ch = 0; ch < NCH; ++ch) {
        const size_t slot = ((size_t)ch * DINNER + c) * 16 + n;
        const float dec = __expf(Av * dsum[(size_t)ch * DINNER + c]);
        const float he  = hend[slot];
        hend[slot] = h;           // h0 for chunk ch
        h = fmaf(dec, h, he);     // h_end of chunk ch
    }
}

// Pass 3: full scan per chunk starting from h0; fused conv+silu+gate; bf16 out.
__global__ __launch_bounds__(256) void scan_pass2(const float* __restrict__ zxbc,
                                                  const float* __restrict__ delta,
                                                  const float* __restrict__ conv_w,
                                                  const float* __restrict__ conv_b,
                                                  const float* __restrict__ A_log,
                                                  const float* __restrict__ Dvec,
                                                  const float* __restrict__ h0buf,
                                                  ushort* __restrict__ ypre) {
    __shared__ float sd[TC][16], sz[TC][16], sB[TC][16], sC[TC][16], sx[TC][16];
    const int g = blockIdx.x, ch = blockIdx.y;
    const int tid = threadIdx.x;
    const int p = tid >> 4, n = tid & 15;
    const int c = (g << 4) + p;
    const int t0 = ch * TC;
    const float Av = -expf(A_log[(c << 4) + n]);
    const float Dv = Dvec[c];
    const float4 w4 = *(const float4*)(conv_w + c * 4);
    const float cb = conv_b[c];

    const int r = tid >> 2, q = (tid & 3) << 2;
    *(float4*)&sd[r][q] = *(const float4*)(delta + (size_t)(t0 + r) * DINNER + (g << 4) + q);
    *(float4*)&sz[r][q] = *(const float4*)(zxbc + (size_t)(t0 + r) * ZXBC_N + OFF_Z + (g << 4) + q);
    *(float4*)&sB[r][q] = *(const float4*)(zxbc + (size_t)(t0 + r) * ZXBC_N + OFF_B + ((g >> 3) << 4) + q);
    *(float4*)&sC[r][q] = *(const float4*)(zxbc + (size_t)(t0 + r) * ZXBC_N + OFF_C + (g << 4) + q);
    *(float4*)&sx[r][q] = *(const float4*)(zxbc + (size_t)(t0 + r) * ZXBC_N + OFF_X + ((g >> 3) << 4) + q);

    const size_t xg = OFF_X + ((size_t)(g >> 3) << 4) + p;
    float xm3 = 0.f, xm2 = 0.f, xm1 = 0.f;
    if (ch > 0) {
        xm3 = zxbc[(size_t)(t0 - 3) * ZXBC_N + xg];
        xm2 = zxbc[(size_t)(t0 - 2) * ZXBC_N + xg];
        xm1 = zxbc[(size_t)(t0 - 1) * ZXBC_N + xg];
    }
    float h = h0buf[((size_t)ch * DINNER + c) * 16 + n];
    __syncthreads();
    #pragma unroll 4
    for (int tl = 0; tl < TC; ++tl) {
        const float xt = sx[tl][p];
        const float d  = sd[tl][p];
        const float z  = sz[tl][p];
        const float Bv = sB[tl][n];
        const float Cv = sC[tl][n];
        float u = cb;
        u = fmaf(w4.x, xm3, u); u = fmaf(w4.y, xm2, u);
        u = fmaf(w4.z, xm1, u); u = fmaf(w4.w, xt, u);
        u = silu_f(u);
        xm3 = xm2; xm2 = xm1; xm1 = xt;
        h = fmaf(h, __expf(d * Av), d * u * Bv);
        float yp = h * Cv;
        yp += __shfl_xor(yp, 1);
        yp += __shfl_xor(yp, 2);
        yp += __shfl_xor(yp, 4);
        yp += __shfl_xor(yp, 8);
        if (n == 0) {
            const float yv = fmaf(u, Dv, yp) * silu_f(z);
            ypre[(size_t)(t0 + tl) * DINNER + c] = f2bf(yv);
        }
    }
}

extern "C" void kernel_launch(void* const* d_in, const int* in_sizes, int n_in,
                              void* d_out, int out_size, void* d_ws, size_t ws_size,
                              hipStream_t stream) {
    const float* hidden       = (const float*)d_in[0];
    const float* in_proj_w    = (const float*)d_in[1];
    const float* dt_in_proj_w = (const float*)d_in[2];
    const float* dt_proj_w    = (const float*)d_in[3];
    const float* dt_proj_b    = (const float*)d_in[4];
    const float* conv_w       = (const float*)d_in[5];
    const float* conv_b       = (const float*)d_in[6];
    const float* A_log        = (const float*)d_in[7];
    const float* Dvec         = (const float*)d_in[8];
    const float* out_proj_w   = (const float*)d_in[9];

    // workspace layout (bytes). wbig: in_proj bf16 (37.7MB) until zxbc GEMM,
    // then first 16.8MB = out_proj bf16; tail reused for scan summaries.
    char* wsb = (char*)d_ws;
    float*  zxbc  = (float*) (wsb + 0ull);            // 75,497,472
    float*  delta = (float*) (wsb + 75497472ull);     // 33,554,432
    ushort* ypre  = (ushort*)(wsb + 109051904ull);    // 16,777,216
    ushort* hb    = (ushort*)(wsb + 125829120ull);    //  8,388,608
    ushort* t1b   = (ushort*)(wsb + 134217728ull);    //    524,288
    ushort* wdtib = (ushort*)(wsb + 134742016ull);    //    524,288
    ushort* wdtpb = (ushort*)(wsb + 135266304ull);    //  1,048,576
    ushort* wbig  = (ushort*)(wsb + 136314880ull);    // 37,748,736 -> end 174,063,616
    float*  hend  = (float*) (wsb + 153092096ull);    //  8,388,608 (overlaps wbig tail)
    float*  dsum  = (float*) (wsb + 161480704ull);    //    524,288

    f32_to_bf16<<<4096,  256, 0, stream>>>(hidden,       hb,    1048576);
    f32_to_bf16<<<18432, 256, 0, stream>>>(in_proj_w,    wbig,  4718592);
    f32_to_bf16<<<256,   256, 0, stream>>>(dt_in_proj_w, wdtib, 65536);
    f32_to_bf16<<<512,   256, 0, stream>>>(dt_proj_w,    wdtpb, 131072);

    // zxbc = hidden @ in_proj_w^T  (fp32 out)
    gemm_bt_bf16<0><<<1152, 256, 0, stream>>>(hb, wbig, zxbc, nullptr, SEQ, ZXBC_N, DMODEL);
    // wbig now free -> out_proj bf16 (into first 16.8MB of wbig)
    f32_to_bf16<<<8192, 256, 0, stream>>>(out_proj_w, wbig, 2097152);
    // t1 = hidden @ dt_in_proj_w^T  (bf16 out)
    gemm_bt_bf16<2><<<16, 256, 0, stream>>>(hb, wdtib, t1b, nullptr, SEQ, DTRANK, DMODEL);
    // delta = softplus(t1 @ dt_proj_w^T + dt_proj_b)  (fp32 out)
    gemm_bt_bf16<1><<<512, 256, 0, stream>>>(t1b, wdtpb, delta, dt_proj_b, SEQ, DINNER, DTRANK);

    // chunked scan
    scan_pass1<<<dim3(NGROUP, NCH), 256, 0, stream>>>(zxbc, delta, conv_w, conv_b, A_log, hend, dsum);
    scan_mid  <<<256, 256, 0, stream>>>(A_log, hend, dsum);
    scan_pass2<<<dim3(NGROUP, NCH), 256, 0, stream>>>(zxbc, delta, conv_w, conv_b, A_log, Dvec, hend, ypre);

    // out = ypre @ out_proj_w^T  (fp32 out)
    gemm_bt_bf16<0><<<256, 256, 0, stream>>>(ypre, wbig, (float*)d_out, nullptr, SEQ, DMODEL, DINNER);
}

// Round 4
// 464.653 us; speedup vs baseline: 5.5736x; 1.3568x over previous
//
#include <hip/hip_runtime.h>
#include <hip/hip_bf16.h>

#define SEQ     2048
#define DMODEL  2048
#define DINNER  4096
#define DXB     512
#define DSTATE  16
#define DTRANK  128
#define ZXBC_N  9216   // 2*DXB + 2*DINNER
#define NGROUP  256    // NUM_C_HEAD
#define NCH     32     // time chunks
#define TC      64     // steps per chunk

// zxbc row layout: [ z:0..4096 | x:4096..4608 | B:4608..5120 | C:5120..9216 ]
#define OFF_Z 0
#define OFF_X 4096
#define OFF_B 4608
#define OFF_C 5120

typedef __attribute__((ext_vector_type(8))) short short8;
typedef __attribute__((ext_vector_type(4))) float f32x4;

__device__ __forceinline__ float softplus_f(float x) {
    return x > 0.f ? x + log1pf(expf(-x)) : log1pf(expf(x));
}
__device__ __forceinline__ float silu_f(float x) {
    return x / (1.f + __expf(-x));
}
__device__ __forceinline__ ushort f2bf(float f) {
    union { float f; unsigned u; } v; v.f = f;
    unsigned r = v.u + 0x7fffu + ((v.u >> 16) & 1u);   // RNE
    return (ushort)(r >> 16);
}

__global__ __launch_bounds__(256) void f32_to_bf16(const float* __restrict__ in,
                                                   ushort* __restrict__ out, int n4) {
    int i = blockIdx.x * 256 + threadIdx.x;
    if (i < n4) {
        float4 v = ((const float4*)in)[i];
        ushort4 o;
        o.x = f2bf(v.x); o.y = f2bf(v.y); o.z = f2bf(v.z); o.w = f2bf(v.w);
        ((ushort4*)out)[i] = o;
    }
}

#define GLOAD16(gp, lp) __builtin_amdgcn_global_load_lds( \
    (const __attribute__((address_space(1))) void*)(gp), \
    (__attribute__((address_space(3))) void*)(lp), 16, 0, 0)

// C[M,N] = A[M,K] (bf16, row-major) * B[N,K]^T (bf16, row-major), fp32 accumulate.
// EPI 0: f32 out. EPI 1: f32 out = softplus(acc + bias[col]). EPI 2: bf16 out.
template<int EPI>
__global__ __launch_bounds__(256) void gemm_bt_bf16(const ushort* __restrict__ A,
                                                    const ushort* __restrict__ B,
                                                    void* __restrict__ Cout,
                                                    const float* __restrict__ bias,
                                                    int M, int N, int K) {
    __shared__ ushort As[128 * 32];
    __shared__ ushort Bs[128 * 32];
    const int nbx = N >> 7;
    const int nwg = gridDim.x;
    int lin = blockIdx.x;
    if ((nwg & 7) == 0) lin = (lin & 7) * (nwg >> 3) + (lin >> 3);  // XCD swizzle
    const int by = lin / nbx;
    const int bx = lin - by * nbx;
    const int row0 = by << 7, col0 = bx << 7;

    const int tid  = threadIdx.x;
    const int w    = tid >> 6;
    const int lane = tid & 63;

    const int srow = (w << 5) + (lane >> 2);
    const int skb  = (lane & 3) << 3;
    const ushort* ag = A + (size_t)(row0 + srow) * K + skb;
    const ushort* bg = B + (size_t)(col0 + srow) * K + skb;
    ushort* al0 = As + ((w << 5) +  0) * 32;
    ushort* al1 = As + ((w << 5) + 16) * 32;
    ushort* bl0 = Bs + ((w << 5) +  0) * 32;
    ushort* bl1 = Bs + ((w << 5) + 16) * 32;

    const int wm = (w >> 1) << 6;
    const int wn = (w & 1) << 6;
    const int fr = lane & 15;
    const int ko = (lane >> 4) << 3;

    f32x4 acc[4][4] = {};
    for (int k0 = 0; k0 < K; k0 += 32) {
        __syncthreads();
        GLOAD16(ag,                  al0);
        GLOAD16(ag + (size_t)16 * K, al1);
        GLOAD16(bg,                  bl0);
        GLOAD16(bg + (size_t)16 * K, bl1);
        ag += 32; bg += 32;
        __syncthreads();
        short8 af[4], bf[4];
        #pragma unroll
        for (int i = 0; i < 4; ++i)
            af[i] = *(const short8*)(As + (wm + i * 16 + fr) * 32 + ko);
        #pragma unroll
        for (int j = 0; j < 4; ++j)
            bf[j] = *(const short8*)(Bs + (wn + j * 16 + fr) * 32 + ko);
        #pragma unroll
        for (int i = 0; i < 4; ++i)
            #pragma unroll
            for (int j = 0; j < 4; ++j)
                acc[i][j] = __builtin_amdgcn_mfma_f32_16x16x32_bf16(af[i], bf[j], acc[i][j], 0, 0, 0);
    }

    const int orow = row0 + wm + ((lane >> 4) << 2);
    const int ocol = col0 + wn + fr;
    #pragma unroll
    for (int i = 0; i < 4; ++i) {
        #pragma unroll
        for (int r = 0; r < 4; ++r) {
            const int row = orow + i * 16 + r;
            #pragma unroll
            for (int j = 0; j < 4; ++j) {
                const int col = ocol + j * 16;
                float v = acc[i][j][r];
                if (EPI == 1) v = softplus_f(v + bias[col]);
                if (EPI == 2) ((ushort*)Cout)[(size_t)row * N + col] = f2bf(v);
                else          ((float*)Cout)[(size_t)row * N + col] = v;
            }
        }
    }
}

// ---- chunked selective scan, thread = channel (16 states in registers) ----
// Block = 256 channels (16 c-heads, 2 xb-heads), one time-chunk of 64 steps.

// Pass 1: local scan from h=0 -> hend[(ch*DINNER+c)*16+n], dsum[ch*DINNER+c].
__global__ __launch_bounds__(256) void scan_pass1(const float* __restrict__ zxbc,
                                                  const float* __restrict__ delta,
                                                  const float* __restrict__ conv_w,
                                                  const float* __restrict__ conv_b,
                                                  const float* __restrict__ A_log,
                                                  float* __restrict__ hend,
                                                  float* __restrict__ dsum) {
    __shared__ float sB[TC][32];          // [t][xb-head-local*16 + n]
    const int ch  = blockIdx.y;
    const int c0  = blockIdx.x << 8;      // block channel base
    const int tid = threadIdx.x;
    const int c   = c0 + tid;
    const int t0  = ch * TC;
    const int xhl = (tid >> 7) & 1;       // xb-head local (wave-uniform)
    const int xcol = ((c >> 7) << 4) | (c & 15);

    float Av[16];
    #pragma unroll
    for (int q = 0; q < 4; ++q) {
        float4 a4 = *(const float4*)(A_log + (c << 4) + (q << 2));
        Av[q*4+0] = -expf(a4.x); Av[q*4+1] = -expf(a4.y);
        Av[q*4+2] = -expf(a4.z); Av[q*4+3] = -expf(a4.w);
    }
    const float4 w4 = *(const float4*)(conv_w + c * 4);
    const float cb = conv_b[c];

    // stage B for all 64 steps: 64 rows x 32 floats = 512 float4, 2 per thread
    {
        const int f = tid & 7;
        const int xb0 = (c0 >> 7) << 4;   // B column base (32 cols)
        #pragma unroll
        for (int k = 0; k < 2; ++k) {
            const int tl = (tid >> 3) + (k << 5);
            float4 v = *(const float4*)(zxbc + (size_t)(t0 + tl) * ZXBC_N + OFF_B + xb0 + (f << 2));
            *(float4*)&sB[tl][f << 2] = v;
        }
    }

    // conv history
    float xm3 = 0.f, xm2 = 0.f, xm1 = 0.f;
    if (ch > 0) {
        xm3 = zxbc[(size_t)(t0 - 3) * ZXBC_N + OFF_X + xcol];
        xm2 = zxbc[(size_t)(t0 - 2) * ZXBC_N + OFF_X + xcol];
        xm1 = zxbc[(size_t)(t0 - 1) * ZXBC_N + OFF_X + xcol];
    }
    float dcur = delta[(size_t)t0 * DINNER + c];
    float xcur = zxbc[(size_t)t0 * ZXBC_N + OFF_X + xcol];

    float h[16];
    #pragma unroll
    for (int n = 0; n < 16; ++n) h[n] = 0.f;
    float Dc = 0.f;
    __syncthreads();

    #pragma unroll 4
    for (int tl = 0; tl < TC; ++tl) {
        float dn = 0.f, xn = 0.f;
        if (tl < TC - 1) {
            const size_t t1 = (size_t)(t0 + tl + 1);
            dn = delta[t1 * DINNER + c];
            xn = zxbc[t1 * ZXBC_N + OFF_X + xcol];
        }
        float Bv[16];
        *(float4*)(Bv +  0) = *(const float4*)&sB[tl][(xhl << 4) +  0];
        *(float4*)(Bv +  4) = *(const float4*)&sB[tl][(xhl << 4) +  4];
        *(float4*)(Bv +  8) = *(const float4*)&sB[tl][(xhl << 4) +  8];
        *(float4*)(Bv + 12) = *(const float4*)&sB[tl][(xhl << 4) + 12];
        float u = cb;
        u = fmaf(w4.x, xm3, u); u = fmaf(w4.y, xm2, u);
        u = fmaf(w4.z, xm1, u); u = fmaf(w4.w, xcur, u);
        u = silu_f(u);
        xm3 = xm2; xm2 = xm1; xm1 = xcur;
        const float du = dcur * u;
        Dc += dcur;
        #pragma unroll
        for (int n = 0; n < 16; ++n) {
            const float dA = __expf(dcur * Av[n]);
            h[n] = fmaf(h[n], dA, du * Bv[n]);
        }
        dcur = dn; xcur = xn;
    }
    float* hp = hend + ((size_t)ch * DINNER + c) * 16;
    #pragma unroll
    for (int q = 0; q < 4; ++q)
        *(float4*)(hp + (q << 2)) = make_float4(h[q*4+0], h[q*4+1], h[q*4+2], h[q*4+3]);
    dsum[(size_t)ch * DINNER + c] = Dc;
}

// Pass 2 (tiny): sequential combine over chunks per state (c,n).
__global__ __launch_bounds__(256) void scan_mid(const float* __restrict__ A_log,
                                                float* __restrict__ hend,
                                                const float* __restrict__ dsum) {
    const int idx = blockIdx.x * 256 + threadIdx.x;   // 0..65535
    const int c = idx >> 4, n = idx & 15;
    const float Av = -expf(A_log[(c << 4) + n]);
    float h = 0.f;
    #pragma unroll
    for (int ch = 0; ch < NCH; ++ch) {
        const size_t slot = ((size_t)ch * DINNER + c) * 16 + n;
        const float dec = __expf(Av * dsum[(size_t)ch * DINNER + c]);
        const float he  = hend[slot];
        hend[slot] = h;           // h0 for chunk ch
        h = fmaf(dec, h, he);     // h_end of chunk ch
    }
}

// Pass 3: full scan from h0, fused conv+silu+gate, bf16 out.
// C staged in LDS per 32-step half; next half's loads issued before compute (T14).
__global__ __launch_bounds__(256) void scan_pass2(const float* __restrict__ zxbc,
                                                  const float* __restrict__ delta,
                                                  const float* __restrict__ conv_w,
                                                  const float* __restrict__ conv_b,
                                                  const float* __restrict__ A_log,
                                                  const float* __restrict__ Dvec,
                                                  const float* __restrict__ h0buf,
                                                  ushort* __restrict__ ypre) {
    __shared__ float sB[32][32];          // [t-local][xbh-local*16+n]
    __shared__ float sC[32][256];         // [t-local][head-local*16+n]
    const int ch  = blockIdx.y;
    const int c0  = blockIdx.x << 8;
    const int tid = threadIdx.x;
    const int c   = c0 + tid;
    const int t0  = ch * TC;
    const int xhl = (tid >> 7) & 1;
    const int gl  = tid >> 4;             // head-local 0..15
    const int xcol = ((c >> 7) << 4) | (c & 15);

    float Av[16];
    #pragma unroll
    for (int q = 0; q < 4; ++q) {
        float4 a4 = *(const float4*)(A_log + (c << 4) + (q << 2));
        Av[q*4+0] = -expf(a4.x); Av[q*4+1] = -expf(a4.y);
        Av[q*4+2] = -expf(a4.z); Av[q*4+3] = -expf(a4.w);
    }
    const float4 w4 = *(const float4*)(conv_w + c * 4);
    const float cb = conv_b[c];
    const float Dv = Dvec[c];

    // stage-load half 0 into regs
    const int bf_ = tid & 7;
    const int btl = tid >> 3;
    const int xb0 = (c0 >> 7) << 4;
    const int cf  = tid & 63;             // float4 col within C row
    const int ctl0 = tid >> 6;            // row base 0..3
    float4 rB, rC[8];
    {
        rB = *(const float4*)(zxbc + (size_t)(t0 + btl) * ZXBC_N + OFF_B + xb0 + (bf_ << 2));
        #pragma unroll
        for (int k = 0; k < 8; ++k) {
            const int tl = ctl0 + (k << 2);
            rC[k] = *(const float4*)(zxbc + (size_t)(t0 + tl) * ZXBC_N + OFF_C + c0 + (cf << 2));
        }
    }

    // conv history + first-step stream values
    float xm3 = 0.f, xm2 = 0.f, xm1 = 0.f;
    if (ch > 0) {
        xm3 = zxbc[(size_t)(t0 - 3) * ZXBC_N + OFF_X + xcol];
        xm2 = zxbc[(size_t)(t0 - 2) * ZXBC_N + OFF_X + xcol];
        xm1 = zxbc[(size_t)(t0 - 1) * ZXBC_N + OFF_X + xcol];
    }
    float dcur = delta[(size_t)t0 * DINNER + c];
    float xcur = zxbc[(size_t)t0 * ZXBC_N + OFF_X + xcol];
    float zcur = zxbc[(size_t)t0 * ZXBC_N + OFF_Z + c];

    float h[16];
    {
        const float* hp = h0buf + ((size_t)ch * DINNER + c) * 16;
        #pragma unroll
        for (int q = 0; q < 4; ++q) {
            float4 v = *(const float4*)(hp + (q << 2));
            h[q*4+0] = v.x; h[q*4+1] = v.y; h[q*4+2] = v.z; h[q*4+3] = v.w;
        }
    }

    for (int hh = 0; hh < 2; ++hh) {
        __syncthreads();                       // LDS free (prev half consumed)
        *(float4*)&sB[btl][bf_ << 2] = rB;     // vmcnt-waited automatically
        #pragma unroll
        for (int k = 0; k < 8; ++k)
            *(float4*)&sC[ctl0 + (k << 2)][cf << 2] = rC[k];
        __syncthreads();
        if (hh == 0) {                         // issue next half's loads now (T14)
            const int th = t0 + 32;
            rB = *(const float4*)(zxbc + (size_t)(th + btl) * ZXBC_N + OFF_B + xb0 + (bf_ << 2));
            #pragma unroll
            for (int k = 0; k < 8; ++k) {
                const int tl = ctl0 + (k << 2);
                rC[k] = *(const float4*)(zxbc + (size_t)(th + tl) * ZXBC_N + OFF_C + c0 + (cf << 2));
            }
        }
        const int tb = t0 + (hh << 5);
        #pragma unroll 4
        for (int tl = 0; tl < 32; ++tl) {
            const int t = tb + tl;
            float dn = 0.f, xn = 0.f, zn = 0.f;
            if (t < t0 + TC - 1) {
                const size_t t1 = (size_t)(t + 1);
                dn = delta[t1 * DINNER + c];
                xn = zxbc[t1 * ZXBC_N + OFF_X + xcol];
                zn = zxbc[t1 * ZXBC_N + OFF_Z + c];
            }
            float Bv[16], Cv[16];
            *(float4*)(Bv +  0) = *(const float4*)&sB[tl][(xhl << 4) +  0];
            *(float4*)(Bv +  4) = *(const float4*)&sB[tl][(xhl << 4) +  4];
            *(float4*)(Bv +  8) = *(const float4*)&sB[tl][(xhl << 4) +  8];
            *(float4*)(Bv + 12) = *(const float4*)&sB[tl][(xhl << 4) + 12];
            *(float4*)(Cv +  0) = *(const float4*)&sC[tl][(gl << 4) +  0];
            *(float4*)(Cv +  4) = *(const float4*)&sC[tl][(gl << 4) +  4];
            *(float4*)(Cv +  8) = *(const float4*)&sC[tl][(gl << 4) +  8];
            *(float4*)(Cv + 12) = *(const float4*)&sC[tl][(gl << 4) + 12];
            float u = cb;
            u = fmaf(w4.x, xm3, u); u = fmaf(w4.y, xm2, u);
            u = fmaf(w4.z, xm1, u); u = fmaf(w4.w, xcur, u);
            u = silu_f(u);
            xm3 = xm2; xm2 = xm1; xm1 = xcur;
            const float du = dcur * u;
            float y0 = 0.f, y1 = 0.f, y2 = 0.f, y3 = 0.f;
            #pragma unroll
            for (int q = 0; q < 4; ++q) {
                const float dA0 = __expf(dcur * Av[q*4+0]);
                const float dA1 = __expf(dcur * Av[q*4+1]);
                const float dA2 = __expf(dcur * Av[q*4+2]);
                const float dA3 = __expf(dcur * Av[q*4+3]);
                h[q*4+0] = fmaf(h[q*4+0], dA0, du * Bv[q*4+0]);
                h[q*4+1] = fmaf(h[q*4+1], dA1, du * Bv[q*4+1]);
                h[q*4+2] = fmaf(h[q*4+2], dA2, du * Bv[q*4+2]);
                h[q*4+3] = fmaf(h[q*4+3], dA3, du * Bv[q*4+3]);
                y0 = fmaf(h[q*4+0], Cv[q*4+0], y0);
                y1 = fmaf(h[q*4+1], Cv[q*4+1], y1);
                y2 = fmaf(h[q*4+2], Cv[q*4+2], y2);
                y3 = fmaf(h[q*4+3], Cv[q*4+3], y3);
            }
            const float y = (y0 + y1) + (y2 + y3);
            const float yv = fmaf(u, Dv, y) * silu_f(zcur);
            ypre[(size_t)t * DINNER + c] = f2bf(yv);
            dcur = dn; xcur = xn; zcur = zn;
        }
    }
}

extern "C" void kernel_launch(void* const* d_in, const int* in_sizes, int n_in,
                              void* d_out, int out_size, void* d_ws, size_t ws_size,
                              hipStream_t stream) {
    const float* hidden       = (const float*)d_in[0];
    const float* in_proj_w    = (const float*)d_in[1];
    const float* dt_in_proj_w = (const float*)d_in[2];
    const float* dt_proj_w    = (const float*)d_in[3];
    const float* dt_proj_b    = (const float*)d_in[4];
    const float* conv_w       = (const float*)d_in[5];
    const float* conv_b       = (const float*)d_in[6];
    const float* A_log        = (const float*)d_in[7];
    const float* Dvec         = (const float*)d_in[8];
    const float* out_proj_w   = (const float*)d_in[9];

    // workspace layout (bytes) — identical to round 3 (known-good, ~174MB peak)
    char* wsb = (char*)d_ws;
    float*  zxbc  = (float*) (wsb + 0ull);            // 75,497,472
    float*  delta = (float*) (wsb + 75497472ull);     // 33,554,432
    ushort* ypre  = (ushort*)(wsb + 109051904ull);    // 16,777,216
    ushort* hb    = (ushort*)(wsb + 125829120ull);    //  8,388,608
    ushort* t1b   = (ushort*)(wsb + 134217728ull);    //    524,288
    ushort* wdtib = (ushort*)(wsb + 134742016ull);    //    524,288
    ushort* wdtpb = (ushort*)(wsb + 135266304ull);    //  1,048,576
    ushort* wbig  = (ushort*)(wsb + 136314880ull);    // 37,748,736 -> end 174,063,616
    float*  hend  = (float*) (wsb + 153092096ull);    //  8,388,608 (overlaps wbig tail)
    float*  dsum  = (float*) (wsb + 161480704ull);    //    524,288

    f32_to_bf16<<<4096,  256, 0, stream>>>(hidden,       hb,    1048576);
    f32_to_bf16<<<18432, 256, 0, stream>>>(in_proj_w,    wbig,  4718592);
    f32_to_bf16<<<256,   256, 0, stream>>>(dt_in_proj_w, wdtib, 65536);
    f32_to_bf16<<<512,   256, 0, stream>>>(dt_proj_w,    wdtpb, 131072);

    // zxbc = hidden @ in_proj_w^T  (fp32 out)
    gemm_bt_bf16<0><<<1152, 256, 0, stream>>>(hb, wbig, zxbc, nullptr, SEQ, ZXBC_N, DMODEL);
    // wbig now free -> out_proj bf16 (into first 16.8MB of wbig)
    f32_to_bf16<<<8192, 256, 0, stream>>>(out_proj_w, wbig, 2097152);
    // t1 = hidden @ dt_in_proj_w^T  (bf16 out)
    gemm_bt_bf16<2><<<16, 256, 0, stream>>>(hb, wdtib, t1b, nullptr, SEQ, DTRANK, DMODEL);
    // delta = softplus(t1 @ dt_proj_w^T + dt_proj_b)  (fp32 out)
    gemm_bt_bf16<1><<<512, 256, 0, stream>>>(t1b, wdtpb, delta, dt_proj_b, SEQ, DINNER, DTRANK);

    // chunked scan (thread = channel)
    scan_pass1<<<dim3(16, NCH), 256, 0, stream>>>(zxbc, delta, conv_w, conv_b, A_log, hend, dsum);
    scan_mid  <<<256, 256, 0, stream>>>(A_log, hend, dsum);
    scan_pass2<<<dim3(16, NCH), 256, 0, stream>>>(zxbc, delta, conv_w, conv_b, A_log, Dvec, hend, ypre);

    // out = ypre @ out_proj_w^T  (fp32 out)
    gemm_bt_bf16<0><<<256, 256, 0, stream>>>(ypre, wbig, (float*)d_out, nullptr, SEQ, DMODEL, DINNER);
}

// Round 5
// 393.569 us; speedup vs baseline: 6.5803x; 1.1806x over previous
//
#include <hip/hip_runtime.h>
#include <hip/hip_bf16.h>

#define SEQ     2048
#define DMODEL  2048
#define DINNER  4096
#define DXB     512
#define DSTATE  16
#define DTRANK  128
#define ZXBC_N  9216   // 2*DXB + 2*DINNER
#define NGROUP  256    // NUM_C_HEAD
#define NCH     32     // time chunks
#define TC      64     // steps per chunk

// zxbc row layout: [ z:0..4096 | x:4096..4608 | B:4608..5120 | C:5120..9216 ]
#define OFF_Z 0
#define OFF_X 4096
#define OFF_B 4608
#define OFF_C 5120

typedef __attribute__((ext_vector_type(8))) short short8;
typedef __attribute__((ext_vector_type(4))) float f32x4;

__device__ __forceinline__ float softplus_f(float x) {
    return x > 0.f ? x + log1pf(expf(-x)) : log1pf(expf(x));
}
__device__ __forceinline__ float silu_f(float x) {
    return x / (1.f + __expf(-x));
}
__device__ __forceinline__ ushort f2bf(float f) {
    union { float f; unsigned u; } v; v.f = f;
    unsigned r = v.u + 0x7fffu + ((v.u >> 16) & 1u);   // RNE
    return (ushort)(r >> 16);
}

__global__ __launch_bounds__(256) void f32_to_bf16(const float* __restrict__ in,
                                                   ushort* __restrict__ out, int n4) {
    int i = blockIdx.x * 256 + threadIdx.x;
    if (i < n4) {
        float4 v = ((const float4*)in)[i];
        ushort4 o;
        o.x = f2bf(v.x); o.y = f2bf(v.y); o.z = f2bf(v.z); o.w = f2bf(v.w);
        ((ushort4*)out)[i] = o;
    }
}

// fused convert of the 4 leading f32->bf16 conversions (one launch)
__global__ __launch_bounds__(256) void cvt4_kernel(const float* __restrict__ h,   ushort* __restrict__ hb,
                                                   const float* __restrict__ ip,  ushort* __restrict__ ipb,
                                                   const float* __restrict__ di,  ushort* __restrict__ dib,
                                                   const float* __restrict__ dp,  ushort* __restrict__ dpb) {
    const int b = blockIdx.x;
    const float* src; ushort* dst; int off;
    if (b < 4096)        { src = h;  dst = hb;  off = b; }
    else if (b < 22528)  { src = ip; dst = ipb; off = b - 4096; }
    else if (b < 22784)  { src = di; dst = dib; off = b - 22528; }
    else                 { src = dp; dst = dpb; off = b - 22784; }
    const int i = off * 256 + threadIdx.x;
    float4 v = ((const float4*)src)[i];
    ushort4 o;
    o.x = f2bf(v.x); o.y = f2bf(v.y); o.z = f2bf(v.z); o.w = f2bf(v.w);
    ((ushort4*)dst)[i] = o;
}

#define GLOAD16(gp, lp) __builtin_amdgcn_global_load_lds( \
    (const __attribute__((address_space(1))) void*)(gp), \
    (__attribute__((address_space(3))) void*)(lp), 16, 0, 0)

// C[M,N] = A[M,K] (bf16, row-major, row stride = K*gridDim.y) * B[N,K]^T, fp32 acc.
// BK=64, 128x128 tile, 4 waves, XOR-swizzled LDS (pre-swizzled global source,
// swizzled ds_read: rule-21 both-sides). blockIdx.y = split-K slice (K = per-slice
// length); EPI0 writes f32 to Cout + y*M*N. EPI1: softplus(acc+bias). EPI2: bf16.
template<int EPI>
__global__ __launch_bounds__(256, 4) void gemm_bt_bf16(const ushort* __restrict__ A,
                                                       const ushort* __restrict__ B,
                                                       void* __restrict__ Cout,
                                                       const float* __restrict__ bias,
                                                       int M, int N, int K) {
    __shared__ ushort As[128 * 64];
    __shared__ ushort Bs[128 * 64];
    const int nbx = N >> 7;
    const int nwg = gridDim.x;
    int lin = blockIdx.x;
    if ((nwg & 7) == 0) lin = (lin & 7) * (nwg >> 3) + (lin >> 3);  // XCD swizzle
    const int by = lin / nbx;
    const int bx = lin - by * nbx;
    const int row0 = by << 7, col0 = bx << 7;

    const int tid  = threadIdx.x;
    const int w    = tid >> 6;
    const int lane = tid & 63;
    const size_t kstride = (size_t)K * gridDim.y;
    const size_t koff    = (size_t)blockIdx.y * K;
    const size_t cbase   = (size_t)blockIdx.y * M * N;

    // staging: wave w fills rows [32w,32w+32); 4 instrs x 8 rows each for A and B.
    // physical LDS is linear; global source pre-swizzled: logical slot = (l&7)^(l>>3)
    const int lrow  = lane >> 3;               // 0..7
    const int lslot = (lane & 7) ^ lrow;       // pre-swizzle (row&7 == lrow here)
    const ushort* ag = A + (size_t)(row0 + (w << 5) + lrow) * kstride + koff + (lslot << 3);
    const ushort* bg = B + (size_t)(col0 + (w << 5) + lrow) * kstride + koff + (lslot << 3);
    ushort* asb = As + ((w << 5) << 6);        // (w*32) rows * 64 elems
    ushort* bsb = Bs + ((w << 5) << 6);

    const int wm = (w >> 1) << 6;
    const int wn = (w & 1) << 6;
    const int fr = lane & 15;
    const int kq = lane >> 4;                  // 0..3
    const int f7 = fr & 7;

    f32x4 acc[4][4] = {};
    for (int k0 = 0; k0 < K; k0 += 64) {
        __syncthreads();
        #pragma unroll
        for (int k = 0; k < 4; ++k) {
            GLOAD16(ag + (size_t)(k << 3) * kstride + k0, asb + (k << 9));
            GLOAD16(bg + (size_t)(k << 3) * kstride + k0, bsb + (k << 9));
        }
        __syncthreads();   // drains vmcnt before reads (2-phase known-safe)
        #pragma unroll
        for (int ks = 0; ks < 2; ++ks) {
            const int ps = (((ks << 2) + kq) ^ f7) << 3;   // swizzled slot bytes/2
            short8 af[4], bf[4];
            #pragma unroll
            for (int i = 0; i < 4; ++i)
                af[i] = *(const short8*)(As + ((wm + i * 16 + fr) << 6) + ps);
            #pragma unroll
            for (int j = 0; j < 4; ++j)
                bf[j] = *(const short8*)(Bs + ((wn + j * 16 + fr) << 6) + ps);
            #pragma unroll
            for (int i = 0; i < 4; ++i)
                #pragma unroll
                for (int j = 0; j < 4; ++j)
                    acc[i][j] = __builtin_amdgcn_mfma_f32_16x16x32_bf16(af[i], bf[j], acc[i][j], 0, 0, 0);
        }
    }

    // C/D layout: col = lane&15, row = (lane>>4)*4 + r  [m89-verified]
    const int orow = row0 + wm + (kq << 2);
    const int ocol = col0 + wn + fr;
    #pragma unroll
    for (int i = 0; i < 4; ++i) {
        #pragma unroll
        for (int r = 0; r < 4; ++r) {
            const int row = orow + i * 16 + r;
            #pragma unroll
            for (int j = 0; j < 4; ++j) {
                const int col = ocol + j * 16;
                float v = acc[i][j][r];
                if (EPI == 1) v = softplus_f(v + bias[col]);
                if (EPI == 2) ((ushort*)Cout)[(size_t)row * N + col] = f2bf(v);
                else          ((float*)Cout)[cbase + (size_t)row * N + col] = v;
            }
        }
    }
}

// reduce 8 split-K partials (f32) -> bf16 t1
__global__ __launch_bounds__(256) void t1_reduce(const float* __restrict__ part,
                                                 ushort* __restrict__ out) {
    const int i = blockIdx.x * 256 + threadIdx.x;   // f4 index, 65536 total
    float4 s = ((const float4*)part)[i];
    #pragma unroll
    for (int z = 1; z < 8; ++z) {
        float4 p = ((const float4*)part)[z * 65536 + i];
        s.x += p.x; s.y += p.y; s.z += p.z; s.w += p.w;
    }
    ushort4 o;
    o.x = f2bf(s.x); o.y = f2bf(s.y); o.z = f2bf(s.z); o.w = f2bf(s.w);
    ((ushort4*)out)[i] = o;
}

// ---- chunked selective scan, thread = channel (16 states in registers) ----

// Pass 1: local scan from h=0 -> hend[(ch*DINNER+c)*16+n], dsum[ch*DINNER+c].
__global__ __launch_bounds__(256) void scan_pass1(const float* __restrict__ zxbc,
                                                  const float* __restrict__ delta,
                                                  const float* __restrict__ conv_w,
                                                  const float* __restrict__ conv_b,
                                                  const float* __restrict__ A_log,
                                                  float* __restrict__ hend,
                                                  float* __restrict__ dsum) {
    __shared__ float sB[TC][32];          // [t][xb-head-local*16 + n]
    const int ch  = blockIdx.y;
    const int c0  = blockIdx.x << 8;      // block channel base
    const int tid = threadIdx.x;
    const int c   = c0 + tid;
    const int t0  = ch * TC;
    const int xhl = (tid >> 7) & 1;       // xb-head local (wave-uniform)
    const int xcol = ((c >> 7) << 4) | (c & 15);

    float Av[16];
    #pragma unroll
    for (int q = 0; q < 4; ++q) {
        float4 a4 = *(const float4*)(A_log + (c << 4) + (q << 2));
        Av[q*4+0] = -expf(a4.x); Av[q*4+1] = -expf(a4.y);
        Av[q*4+2] = -expf(a4.z); Av[q*4+3] = -expf(a4.w);
    }
    const float4 w4 = *(const float4*)(conv_w + c * 4);
    const float cb = conv_b[c];

    {
        const int f = tid & 7;
        const int xb0 = (c0 >> 7) << 4;   // B column base (32 cols)
        #pragma unroll
        for (int k = 0; k < 2; ++k) {
            const int tl = (tid >> 3) + (k << 5);
            float4 v = *(const float4*)(zxbc + (size_t)(t0 + tl) * ZXBC_N + OFF_B + xb0 + (f << 2));
            *(float4*)&sB[tl][f << 2] = v;
        }
    }

    float xm3 = 0.f, xm2 = 0.f, xm1 = 0.f;
    if (ch > 0) {
        xm3 = zxbc[(size_t)(t0 - 3) * ZXBC_N + OFF_X + xcol];
        xm2 = zxbc[(size_t)(t0 - 2) * ZXBC_N + OFF_X + xcol];
        xm1 = zxbc[(size_t)(t0 - 1) * ZXBC_N + OFF_X + xcol];
    }
    float dcur = delta[(size_t)t0 * DINNER + c];
    float xcur = zxbc[(size_t)t0 * ZXBC_N + OFF_X + xcol];

    float h[16];
    #pragma unroll
    for (int n = 0; n < 16; ++n) h[n] = 0.f;
    float Dc = 0.f;
    __syncthreads();

    #pragma unroll 4
    for (int tl = 0; tl < TC; ++tl) {
        float dn = 0.f, xn = 0.f;
        if (tl < TC - 1) {
            const size_t t1 = (size_t)(t0 + tl + 1);
            dn = delta[t1 * DINNER + c];
            xn = zxbc[t1 * ZXBC_N + OFF_X + xcol];
        }
        float Bv[16];
        *(float4*)(Bv +  0) = *(const float4*)&sB[tl][(xhl << 4) +  0];
        *(float4*)(Bv +  4) = *(const float4*)&sB[tl][(xhl << 4) +  4];
        *(float4*)(Bv +  8) = *(const float4*)&sB[tl][(xhl << 4) +  8];
        *(float4*)(Bv + 12) = *(const float4*)&sB[tl][(xhl << 4) + 12];
        float u = cb;
        u = fmaf(w4.x, xm3, u); u = fmaf(w4.y, xm2, u);
        u = fmaf(w4.z, xm1, u); u = fmaf(w4.w, xcur, u);
        u = silu_f(u);
        xm3 = xm2; xm2 = xm1; xm1 = xcur;
        const float du = dcur * u;
        Dc += dcur;
        #pragma unroll
        for (int n = 0; n < 16; ++n) {
            const float dA = __expf(dcur * Av[n]);
            h[n] = fmaf(h[n], dA, du * Bv[n]);
        }
        dcur = dn; xcur = xn;
    }
    float* hp = hend + ((size_t)ch * DINNER + c) * 16;
    #pragma unroll
    for (int q = 0; q < 4; ++q)
        *(float4*)(hp + (q << 2)) = make_float4(h[q*4+0], h[q*4+1], h[q*4+2], h[q*4+3]);
    dsum[(size_t)ch * DINNER + c] = Dc;
}

// Pass 2 (tiny): sequential combine over chunks per state (c,n).
__global__ __launch_bounds__(256) void scan_mid(const float* __restrict__ A_log,
                                                float* __restrict__ hend,
                                                const float* __restrict__ dsum) {
    const int idx = blockIdx.x * 256 + threadIdx.x;   // 0..65535
    const int c = idx >> 4, n = idx & 15;
    const float Av = -expf(A_log[(c << 4) + n]);
    float h = 0.f;
    #pragma unroll
    for (int ch = 0; ch < NCH; ++ch) {
        const size_t slot = ((size_t)ch * DINNER + c) * 16 + n;
        const float dec = __expf(Av * dsum[(size_t)ch * DINNER + c]);
        const float he  = hend[slot];
        hend[slot] = h;           // h0 for chunk ch
        h = fmaf(dec, h, he);     // h_end of chunk ch
    }
}

// Pass 3: full scan from h0, fused conv+silu+gate, bf16 out.
__global__ __launch_bounds__(256) void scan_pass2(const float* __restrict__ zxbc,
                                                  const float* __restrict__ delta,
                                                  const float* __restrict__ conv_w,
                                                  const float* __restrict__ conv_b,
                                                  const float* __restrict__ A_log,
                                                  const float* __restrict__ Dvec,
                                                  const float* __restrict__ h0buf,
                                                  ushort* __restrict__ ypre) {
    __shared__ float sB[32][32];
    __shared__ float sC[32][256];
    const int ch  = blockIdx.y;
    const int c0  = blockIdx.x << 8;
    const int tid = threadIdx.x;
    const int c   = c0 + tid;
    const int t0  = ch * TC;
    const int xhl = (tid >> 7) & 1;
    const int gl  = tid >> 4;
    const int xcol = ((c >> 7) << 4) | (c & 15);

    float Av[16];
    #pragma unroll
    for (int q = 0; q < 4; ++q) {
        float4 a4 = *(const float4*)(A_log + (c << 4) + (q << 2));
        Av[q*4+0] = -expf(a4.x); Av[q*4+1] = -expf(a4.y);
        Av[q*4+2] = -expf(a4.z); Av[q*4+3] = -expf(a4.w);
    }
    const float4 w4 = *(const float4*)(conv_w + c * 4);
    const float cb = conv_b[c];
    const float Dv = Dvec[c];

    const int bf_ = tid & 7;
    const int btl = tid >> 3;
    const int xb0 = (c0 >> 7) << 4;
    const int cf  = tid & 63;
    const int ctl0 = tid >> 6;
    float4 rB, rC[8];
    {
        rB = *(const float4*)(zxbc + (size_t)(t0 + btl) * ZXBC_N + OFF_B + xb0 + (bf_ << 2));
        #pragma unroll
        for (int k = 0; k < 8; ++k) {
            const int tl = ctl0 + (k << 2);
            rC[k] = *(const float4*)(zxbc + (size_t)(t0 + tl) * ZXBC_N + OFF_C + c0 + (cf << 2));
        }
    }

    float xm3 = 0.f, xm2 = 0.f, xm1 = 0.f;
    if (ch > 0) {
        xm3 = zxbc[(size_t)(t0 - 3) * ZXBC_N + OFF_X + xcol];
        xm2 = zxbc[(size_t)(t0 - 2) * ZXBC_N + OFF_X + xcol];
        xm1 = zxbc[(size_t)(t0 - 1) * ZXBC_N + OFF_X + xcol];
    }
    float dcur = delta[(size_t)t0 * DINNER + c];
    float xcur = zxbc[(size_t)t0 * ZXBC_N + OFF_X + xcol];
    float zcur = zxbc[(size_t)t0 * ZXBC_N + OFF_Z + c];

    float h[16];
    {
        const float* hp = h0buf + ((size_t)ch * DINNER + c) * 16;
        #pragma unroll
        for (int q = 0; q < 4; ++q) {
            float4 v = *(const float4*)(hp + (q << 2));
            h[q*4+0] = v.x; h[q*4+1] = v.y; h[q*4+2] = v.z; h[q*4+3] = v.w;
        }
    }

    for (int hh = 0; hh < 2; ++hh) {
        __syncthreads();
        *(float4*)&sB[btl][bf_ << 2] = rB;
        #pragma unroll
        for (int k = 0; k < 8; ++k)
            *(float4*)&sC[ctl0 + (k << 2)][cf << 2] = rC[k];
        __syncthreads();
        if (hh == 0) {
            const int th = t0 + 32;
            rB = *(const float4*)(zxbc + (size_t)(th + btl) * ZXBC_N + OFF_B + xb0 + (bf_ << 2));
            #pragma unroll
            for (int k = 0; k < 8; ++k) {
                const int tl = ctl0 + (k << 2);
                rC[k] = *(const float4*)(zxbc + (size_t)(th + tl) * ZXBC_N + OFF_C + c0 + (cf << 2));
            }
        }
        const int tb = t0 + (hh << 5);
        #pragma unroll 4
        for (int tl = 0; tl < 32; ++tl) {
            const int t = tb + tl;
            float dn = 0.f, xn = 0.f, zn = 0.f;
            if (t < t0 + TC - 1) {
                const size_t t1 = (size_t)(t + 1);
                dn = delta[t1 * DINNER + c];
                xn = zxbc[t1 * ZXBC_N + OFF_X + xcol];
                zn = zxbc[t1 * ZXBC_N + OFF_Z + c];
            }
            float Bv[16], Cv[16];
            *(float4*)(Bv +  0) = *(const float4*)&sB[tl][(xhl << 4) +  0];
            *(float4*)(Bv +  4) = *(const float4*)&sB[tl][(xhl << 4) +  4];
            *(float4*)(Bv +  8) = *(const float4*)&sB[tl][(xhl << 4) +  8];
            *(float4*)(Bv + 12) = *(const float4*)&sB[tl][(xhl << 4) + 12];
            *(float4*)(Cv +  0) = *(const float4*)&sC[tl][(gl << 4) +  0];
            *(float4*)(Cv +  4) = *(const float4*)&sC[tl][(gl << 4) +  4];
            *(float4*)(Cv +  8) = *(const float4*)&sC[tl][(gl << 4) +  8];
            *(float4*)(Cv + 12) = *(const float4*)&sC[tl][(gl << 4) + 12];
            float u = cb;
            u = fmaf(w4.x, xm3, u); u = fmaf(w4.y, xm2, u);
            u = fmaf(w4.z, xm1, u); u = fmaf(w4.w, xcur, u);
            u = silu_f(u);
            xm3 = xm2; xm2 = xm1; xm1 = xcur;
            const float du = dcur * u;
            float y0 = 0.f, y1 = 0.f, y2 = 0.f, y3 = 0.f;
            #pragma unroll
            for (int q = 0; q < 4; ++q) {
                const float dA0 = __expf(dcur * Av[q*4+0]);
                const float dA1 = __expf(dcur * Av[q*4+1]);
                const float dA2 = __expf(dcur * Av[q*4+2]);
                const float dA3 = __expf(dcur * Av[q*4+3]);
                h[q*4+0] = fmaf(h[q*4+0], dA0, du * Bv[q*4+0]);
                h[q*4+1] = fmaf(h[q*4+1], dA1, du * Bv[q*4+1]);
                h[q*4+2] = fmaf(h[q*4+2], dA2, du * Bv[q*4+2]);
                h[q*4+3] = fmaf(h[q*4+3], dA3, du * Bv[q*4+3]);
                y0 = fmaf(h[q*4+0], Cv[q*4+0], y0);
                y1 = fmaf(h[q*4+1], Cv[q*4+1], y1);
                y2 = fmaf(h[q*4+2], Cv[q*4+2], y2);
                y3 = fmaf(h[q*4+3], Cv[q*4+3], y3);
            }
            const float y = (y0 + y1) + (y2 + y3);
            const float yv = fmaf(u, Dv, y) * silu_f(zcur);
            ypre[(size_t)t * DINNER + c] = f2bf(yv);
            dcur = dn; xcur = xn; zcur = zn;
        }
    }
}

extern "C" void kernel_launch(void* const* d_in, const int* in_sizes, int n_in,
                              void* d_out, int out_size, void* d_ws, size_t ws_size,
                              hipStream_t stream) {
    const float* hidden       = (const float*)d_in[0];
    const float* in_proj_w    = (const float*)d_in[1];
    const float* dt_in_proj_w = (const float*)d_in[2];
    const float* dt_proj_w    = (const float*)d_in[3];
    const float* dt_proj_b    = (const float*)d_in[4];
    const float* conv_w       = (const float*)d_in[5];
    const float* conv_b       = (const float*)d_in[6];
    const float* A_log        = (const float*)d_in[7];
    const float* Dvec         = (const float*)d_in[8];
    const float* out_proj_w   = (const float*)d_in[9];

    // workspace layout (bytes) — same as round 3/4 (known-good, ~174MB peak)
    char* wsb = (char*)d_ws;
    float*  zxbc  = (float*) (wsb + 0ull);            // 75,497,472
    float*  delta = (float*) (wsb + 75497472ull);     // 33,554,432
    ushort* ypre  = (ushort*)(wsb + 109051904ull);    // 16,777,216
    float*  t1part= (float*) (wsb + 109051904ull);    //  8,388,608 (dead before pass2)
    ushort* hb    = (ushort*)(wsb + 125829120ull);    //  8,388,608
    ushort* t1b   = (ushort*)(wsb + 134217728ull);    //    524,288
    ushort* wdtib = (ushort*)(wsb + 134742016ull);    //    524,288
    ushort* wdtpb = (ushort*)(wsb + 135266304ull);    //  1,048,576
    ushort* wbig  = (ushort*)(wsb + 136314880ull);    // 37,748,736 -> end 174,063,616
    float*  hend  = (float*) (wsb + 153092096ull);    //  8,388,608 (overlaps wbig tail)
    float*  dsum  = (float*) (wsb + 161480704ull);    //    524,288

    // fused converts: hidden, in_proj, dt_in_proj, dt_proj
    cvt4_kernel<<<23296, 256, 0, stream>>>(hidden, hb, in_proj_w, wbig,
                                           dt_in_proj_w, wdtib, dt_proj_w, wdtpb);

    // zxbc = hidden @ in_proj_w^T  (fp32 out)
    gemm_bt_bf16<0><<<1152, 256, 0, stream>>>(hb, wbig, zxbc, nullptr, SEQ, ZXBC_N, DMODEL);
    // wbig now free -> out_proj bf16 (first 16.8MB of wbig)
    f32_to_bf16<<<8192, 256, 0, stream>>>(out_proj_w, wbig, 2097152);
    // t1 = hidden @ dt_in_proj_w^T  : split-K x8 partials (f32) then reduce -> bf16
    gemm_bt_bf16<0><<<dim3(16, 8), 256, 0, stream>>>(hb, wdtib, t1part, nullptr, SEQ, DTRANK, 256);
    t1_reduce<<<256, 256, 0, stream>>>(t1part, t1b);
    // delta = softplus(t1 @ dt_proj_w^T + dt_proj_b)  (fp32 out)
    gemm_bt_bf16<1><<<512, 256, 0, stream>>>(t1b, wdtpb, delta, dt_proj_b, SEQ, DINNER, DTRANK);

    // chunked scan (thread = channel)
    scan_pass1<<<dim3(16, NCH), 256, 0, stream>>>(zxbc, delta, conv_w, conv_b, A_log, hend, dsum);
    scan_mid  <<<256, 256, 0, stream>>>(A_log, hend, dsum);
    scan_pass2<<<dim3(16, NCH), 256, 0, stream>>>(zxbc, delta, conv_w, conv_b, A_log, Dvec, hend, ypre);

    // out = ypre @ out_proj_w^T  (fp32 out)
    gemm_bt_bf16<0><<<256, 256, 0, stream>>>(ypre, wbig, (float*)d_out, nullptr, SEQ, DMODEL, DINNER);
}

// Round 6
// 354.767 us; speedup vs baseline: 7.3000x; 1.1094x over previous
//
#include <hip/hip_runtime.h>
#include <hip/hip_bf16.h>

#define SEQ     2048
#define DMODEL  2048
#define DINNER  4096
#define DXB     512
#define DSTATE  16
#define DTRANK  128
#define ZXBC_N  9216   // 2*DXB + 2*DINNER
#define NGROUP  256    // NUM_C_HEAD
#define NCH     32     // time chunks
#define TC      64     // steps per chunk

// zxbc row layout: [ z:0..4096 | x:4096..4608 | B:4608..5120 | C:5120..9216 ]
#define OFF_Z 0
#define OFF_X 4096
#define OFF_B 4608
#define OFF_C 5120

typedef __attribute__((ext_vector_type(8))) short short8;
typedef __attribute__((ext_vector_type(8))) unsigned short us8;
typedef __attribute__((ext_vector_type(4))) float f32x4;

__device__ __forceinline__ float softplus_f(float x) {
    return x > 0.f ? x + log1pf(expf(-x)) : log1pf(expf(x));
}
__device__ __forceinline__ float silu_f(float x) {
    return x / (1.f + __expf(-x));
}
__device__ __forceinline__ ushort f2bf(float f) {
    union { float f; unsigned u; } v; v.f = f;
    unsigned r = v.u + 0x7fffu + ((v.u >> 16) & 1u);   // RNE
    return (ushort)(r >> 16);
}
__device__ __forceinline__ float bf2f(ushort u) {
    union { unsigned u; float f; } v; v.u = (unsigned)u << 16;
    return v.f;
}

__global__ __launch_bounds__(256) void f32_to_bf16(const float* __restrict__ in,
                                                   ushort* __restrict__ out, int n4) {
    int i = blockIdx.x * 256 + threadIdx.x;
    if (i < n4) {
        float4 v = ((const float4*)in)[i];
        ushort4 o;
        o.x = f2bf(v.x); o.y = f2bf(v.y); o.z = f2bf(v.z); o.w = f2bf(v.w);
        ((ushort4*)out)[i] = o;
    }
}

// fused convert of the 4 leading f32->bf16 conversions (one launch)
__global__ __launch_bounds__(256) void cvt4_kernel(const float* __restrict__ h,   ushort* __restrict__ hb,
                                                   const float* __restrict__ ip,  ushort* __restrict__ ipb,
                                                   const float* __restrict__ di,  ushort* __restrict__ dib,
                                                   const float* __restrict__ dp,  ushort* __restrict__ dpb) {
    const int b = blockIdx.x;
    const float* src; ushort* dst; int off;
    if (b < 4096)        { src = h;  dst = hb;  off = b; }
    else if (b < 22528)  { src = ip; dst = ipb; off = b - 4096; }
    else if (b < 22784)  { src = di; dst = dib; off = b - 22528; }
    else                 { src = dp; dst = dpb; off = b - 22784; }
    const int i = off * 256 + threadIdx.x;
    float4 v = ((const float4*)src)[i];
    ushort4 o;
    o.x = f2bf(v.x); o.y = f2bf(v.y); o.z = f2bf(v.z); o.w = f2bf(v.w);
    ((ushort4*)dst)[i] = o;
}

#define GLOAD16(gp, lp) __builtin_amdgcn_global_load_lds( \
    (const __attribute__((address_space(1))) void*)(gp), \
    (__attribute__((address_space(3))) void*)(lp), 16, 0, 0)

// C[M,N] = A[M,K] (bf16, row stride = K*gridDim.y) * B[N,K]^T, fp32 acc.
// BK=64, 128x128 tile, 4 waves, XOR-swizzled LDS (pre-swizzled global source).
// blockIdx.y = split-K slice. EPI0: f32 out at Cout + y*M*N. EPI1: softplus(+bias).
// EPI2: bf16 out.
template<int EPI>
__global__ __launch_bounds__(256, 4) void gemm_bt_bf16(const ushort* __restrict__ A,
                                                       const ushort* __restrict__ B,
                                                       void* __restrict__ Cout,
                                                       const float* __restrict__ bias,
                                                       int M, int N, int K) {
    __shared__ ushort As[128 * 64];
    __shared__ ushort Bs[128 * 64];
    const int nbx = N >> 7;
    const int nwg = gridDim.x;
    int lin = blockIdx.x;
    if ((nwg & 7) == 0) lin = (lin & 7) * (nwg >> 3) + (lin >> 3);  // XCD swizzle
    const int by = lin / nbx;
    const int bx = lin - by * nbx;
    const int row0 = by << 7, col0 = bx << 7;

    const int tid  = threadIdx.x;
    const int w    = tid >> 6;
    const int lane = tid & 63;
    const size_t kstride = (size_t)K * gridDim.y;
    const size_t koff    = (size_t)blockIdx.y * K;
    const size_t cbase   = (size_t)blockIdx.y * M * N;

    const int lrow  = lane >> 3;               // 0..7
    const int lslot = (lane & 7) ^ lrow;       // pre-swizzle source
    const ushort* ag = A + (size_t)(row0 + (w << 5) + lrow) * kstride + koff + (lslot << 3);
    const ushort* bg = B + (size_t)(col0 + (w << 5) + lrow) * kstride + koff + (lslot << 3);
    ushort* asb = As + ((w << 5) << 6);
    ushort* bsb = Bs + ((w << 5) << 6);

    const int wm = (w >> 1) << 6;
    const int wn = (w & 1) << 6;
    const int fr = lane & 15;
    const int kq = lane >> 4;
    const int f7 = fr & 7;

    f32x4 acc[4][4] = {};
    for (int k0 = 0; k0 < K; k0 += 64) {
        __syncthreads();
        #pragma unroll
        for (int k = 0; k < 4; ++k) {
            GLOAD16(ag + (size_t)(k << 3) * kstride + k0, asb + (k << 9));
            GLOAD16(bg + (size_t)(k << 3) * kstride + k0, bsb + (k << 9));
        }
        __syncthreads();
        #pragma unroll
        for (int ks = 0; ks < 2; ++ks) {
            const int ps = (((ks << 2) + kq) ^ f7) << 3;
            short8 af[4], bf[4];
            #pragma unroll
            for (int i = 0; i < 4; ++i)
                af[i] = *(const short8*)(As + ((wm + i * 16 + fr) << 6) + ps);
            #pragma unroll
            for (int j = 0; j < 4; ++j)
                bf[j] = *(const short8*)(Bs + ((wn + j * 16 + fr) << 6) + ps);
            #pragma unroll
            for (int i = 0; i < 4; ++i)
                #pragma unroll
                for (int j = 0; j < 4; ++j)
                    acc[i][j] = __builtin_amdgcn_mfma_f32_16x16x32_bf16(af[i], bf[j], acc[i][j], 0, 0, 0);
        }
    }

    const int orow = row0 + wm + (kq << 2);
    const int ocol = col0 + wn + fr;
    #pragma unroll
    for (int i = 0; i < 4; ++i) {
        #pragma unroll
        for (int r = 0; r < 4; ++r) {
            const int row = orow + i * 16 + r;
            #pragma unroll
            for (int j = 0; j < 4; ++j) {
                const int col = ocol + j * 16;
                float v = acc[i][j][r];
                if (EPI == 1) v = softplus_f(v + bias[col]);
                if (EPI == 2) ((ushort*)Cout)[(size_t)row * N + col] = f2bf(v);
                else          ((float*)Cout)[cbase + (size_t)row * N + col] = v;
            }
        }
    }
}

// reduce 8 split-K partials (f32) -> bf16 t1
__global__ __launch_bounds__(256) void t1_reduce(const float* __restrict__ part,
                                                 ushort* __restrict__ out) {
    const int i = blockIdx.x * 256 + threadIdx.x;   // f4 index, 65536 total
    float4 s = ((const float4*)part)[i];
    #pragma unroll
    for (int z = 1; z < 8; ++z) {
        float4 p = ((const float4*)part)[z * 65536 + i];
        s.x += p.x; s.y += p.y; s.z += p.z; s.w += p.w;
    }
    ushort4 o;
    o.x = f2bf(s.x); o.y = f2bf(s.y); o.z = f2bf(s.z); o.w = f2bf(s.w);
    ((ushort4*)out)[i] = o;
}

// reduce 2 split-K partials (f32) -> f32 final out
__global__ __launch_bounds__(256) void out_reduce2(const float* __restrict__ part,
                                                   float* __restrict__ out) {
    const int i = blockIdx.x * 256 + threadIdx.x;   // f4 index, 1048576 total
    float4 a = ((const float4*)part)[i];
    float4 b = ((const float4*)part)[1048576 + i];
    a.x += b.x; a.y += b.y; a.z += b.z; a.w += b.w;
    ((float4*)out)[i] = a;
}

// ---- chunked selective scan, thread = channel (16 states in registers) ----
// zxbc is bf16 now; LDS tiles and recurrence stay f32.

// Pass 1: local scan from h=0 -> hend[(ch*DINNER+c)*16+n], dsum[ch*DINNER+c].
__global__ __launch_bounds__(256) void scan_pass1(const ushort* __restrict__ zxbc,
                                                  const float* __restrict__ delta,
                                                  const float* __restrict__ conv_w,
                                                  const float* __restrict__ conv_b,
                                                  const float* __restrict__ A_log,
                                                  float* __restrict__ hend,
                                                  float* __restrict__ dsum) {
    __shared__ float sB[TC][32];          // [t][xb-head-local*16 + n]
    const int ch  = blockIdx.y;
    const int c0  = blockIdx.x << 8;
    const int tid = threadIdx.x;
    const int c   = c0 + tid;
    const int t0  = ch * TC;
    const int xhl = (tid >> 7) & 1;
    const int xcol = ((c >> 7) << 4) | (c & 15);

    float Av[16];
    #pragma unroll
    for (int q = 0; q < 4; ++q) {
        float4 a4 = *(const float4*)(A_log + (c << 4) + (q << 2));
        Av[q*4+0] = -expf(a4.x); Av[q*4+1] = -expf(a4.y);
        Av[q*4+2] = -expf(a4.z); Av[q*4+3] = -expf(a4.w);
    }
    const float4 w4 = *(const float4*)(conv_w + c * 4);
    const float cb = conv_b[c];

    // stage B (bf16 -> f32 LDS): 64 rows x 32 cols = 256 x us8
    {
        const int f  = tid & 3;           // us8 group within row
        const int tl = tid >> 2;          // row
        const int xb0 = (c0 >> 7) << 4;
        us8 v = *(const us8*)(zxbc + (size_t)(t0 + tl) * ZXBC_N + OFF_B + xb0 + (f << 3));
        float* dst = &sB[tl][f << 3];
        #pragma unroll
        for (int e = 0; e < 8; ++e) dst[e] = bf2f(v[e]);
    }

    float xm3 = 0.f, xm2 = 0.f, xm1 = 0.f;
    if (ch > 0) {
        xm3 = bf2f(zxbc[(size_t)(t0 - 3) * ZXBC_N + OFF_X + xcol]);
        xm2 = bf2f(zxbc[(size_t)(t0 - 2) * ZXBC_N + OFF_X + xcol]);
        xm1 = bf2f(zxbc[(size_t)(t0 - 1) * ZXBC_N + OFF_X + xcol]);
    }
    float dcur = delta[(size_t)t0 * DINNER + c];
    float xcur = bf2f(zxbc[(size_t)t0 * ZXBC_N + OFF_X + xcol]);

    float h[16];
    #pragma unroll
    for (int n = 0; n < 16; ++n) h[n] = 0.f;
    float Dc = 0.f;
    __syncthreads();

    #pragma unroll 4
    for (int tl = 0; tl < TC; ++tl) {
        float dn = 0.f, xn = 0.f;
        if (tl < TC - 1) {
            const size_t t1 = (size_t)(t0 + tl + 1);
            dn = delta[t1 * DINNER + c];
            xn = bf2f(zxbc[t1 * ZXBC_N + OFF_X + xcol]);
        }
        float Bv[16];
        *(float4*)(Bv +  0) = *(const float4*)&sB[tl][(xhl << 4) +  0];
        *(float4*)(Bv +  4) = *(const float4*)&sB[tl][(xhl << 4) +  4];
        *(float4*)(Bv +  8) = *(const float4*)&sB[tl][(xhl << 4) +  8];
        *(float4*)(Bv + 12) = *(const float4*)&sB[tl][(xhl << 4) + 12];
        float u = cb;
        u = fmaf(w4.x, xm3, u); u = fmaf(w4.y, xm2, u);
        u = fmaf(w4.z, xm1, u); u = fmaf(w4.w, xcur, u);
        u = silu_f(u);
        xm3 = xm2; xm2 = xm1; xm1 = xcur;
        const float du = dcur * u;
        Dc += dcur;
        #pragma unroll
        for (int n = 0; n < 16; ++n) {
            const float dA = __expf(dcur * Av[n]);
            h[n] = fmaf(h[n], dA, du * Bv[n]);
        }
        dcur = dn; xcur = xn;
    }
    float* hp = hend + ((size_t)ch * DINNER + c) * 16;
    #pragma unroll
    for (int q = 0; q < 4; ++q)
        *(float4*)(hp + (q << 2)) = make_float4(h[q*4+0], h[q*4+1], h[q*4+2], h[q*4+3]);
    dsum[(size_t)ch * DINNER + c] = Dc;
}

// Pass 2 (tiny): sequential combine over chunks per state (c,n).
__global__ __launch_bounds__(256) void scan_mid(const float* __restrict__ A_log,
                                                float* __restrict__ hend,
                                                const float* __restrict__ dsum) {
    const int idx = blockIdx.x * 256 + threadIdx.x;   // 0..65535
    const int c = idx >> 4, n = idx & 15;
    const float Av = -expf(A_log[(c << 4) + n]);
    float h = 0.f;
    #pragma unroll
    for (int ch = 0; ch < NCH; ++ch) {
        const size_t slot = ((size_t)ch * DINNER + c) * 16 + n;
        const float dec = __expf(Av * dsum[(size_t)ch * DINNER + c]);
        const float he  = hend[slot];
        hend[slot] = h;           // h0 for chunk ch
        h = fmaf(dec, h, he);     // h_end of chunk ch
    }
}

// Pass 3: full scan from h0, fused conv+silu+gate, bf16 out.
// B/C staged per 32-step half with T14 issue-early/write-late.
__global__ __launch_bounds__(256) void scan_pass2(const ushort* __restrict__ zxbc,
                                                  const float* __restrict__ delta,
                                                  const float* __restrict__ conv_w,
                                                  const float* __restrict__ conv_b,
                                                  const float* __restrict__ A_log,
                                                  const float* __restrict__ Dvec,
                                                  const float* __restrict__ h0buf,
                                                  ushort* __restrict__ ypre) {
    __shared__ float sB[32][32];
    __shared__ float sC[32][256];
    const int ch  = blockIdx.y;
    const int c0  = blockIdx.x << 8;
    const int tid = threadIdx.x;
    const int c   = c0 + tid;
    const int t0  = ch * TC;
    const int xhl = (tid >> 7) & 1;
    const int gl  = tid >> 4;
    const int xcol = ((c >> 7) << 4) | (c & 15);

    float Av[16];
    #pragma unroll
    for (int q = 0; q < 4; ++q) {
        float4 a4 = *(const float4*)(A_log + (c << 4) + (q << 2));
        Av[q*4+0] = -expf(a4.x); Av[q*4+1] = -expf(a4.y);
        Av[q*4+2] = -expf(a4.z); Av[q*4+3] = -expf(a4.w);
    }
    const float4 w4 = *(const float4*)(conv_w + c * 4);
    const float cb = conv_b[c];
    const float Dv = Dvec[c];

    // staging maps
    const int btl = tid >> 3;             // B: row 0..31
    const int bf_ = tid & 7;              // B: ushort4 group (32/4)
    const int xb0 = (c0 >> 7) << 4;
    const int crow = tid >> 5;            // C: row base 0..7
    const int cgrp = tid & 31;            // C: us8 group (256/8)
    ushort4 rB; us8 rC[4];
    {
        rB = *(const ushort4*)(zxbc + (size_t)(t0 + btl) * ZXBC_N + OFF_B + xb0 + (bf_ << 2));
        #pragma unroll
        for (int k = 0; k < 4; ++k) {
            const int row = crow + (k << 3);
            rC[k] = *(const us8*)(zxbc + (size_t)(t0 + row) * ZXBC_N + OFF_C + c0 + (cgrp << 3));
        }
    }

    float xm3 = 0.f, xm2 = 0.f, xm1 = 0.f;
    if (ch > 0) {
        xm3 = bf2f(zxbc[(size_t)(t0 - 3) * ZXBC_N + OFF_X + xcol]);
        xm2 = bf2f(zxbc[(size_t)(t0 - 2) * ZXBC_N + OFF_X + xcol]);
        xm1 = bf2f(zxbc[(size_t)(t0 - 1) * ZXBC_N + OFF_X + xcol]);
    }
    float dcur = delta[(size_t)t0 * DINNER + c];
    float xcur = bf2f(zxbc[(size_t)t0 * ZXBC_N + OFF_X + xcol]);
    float zcur = bf2f(zxbc[(size_t)t0 * ZXBC_N + OFF_Z + c]);

    float h[16];
    {
        const float* hp = h0buf + ((size_t)ch * DINNER + c) * 16;
        #pragma unroll
        for (int q = 0; q < 4; ++q) {
            float4 v = *(const float4*)(hp + (q << 2));
            h[q*4+0] = v.x; h[q*4+1] = v.y; h[q*4+2] = v.z; h[q*4+3] = v.w;
        }
    }

    for (int hh = 0; hh < 2; ++hh) {
        __syncthreads();
        sB[btl][(bf_ << 2) + 0] = bf2f(rB.x);
        sB[btl][(bf_ << 2) + 1] = bf2f(rB.y);
        sB[btl][(bf_ << 2) + 2] = bf2f(rB.z);
        sB[btl][(bf_ << 2) + 3] = bf2f(rB.w);
        #pragma unroll
        for (int k = 0; k < 4; ++k) {
            const int row = crow + (k << 3);
            float* dst = &sC[row][cgrp << 3];
            #pragma unroll
            for (int e = 0; e < 8; ++e) dst[e] = bf2f(rC[k][e]);
        }
        __syncthreads();
        if (hh == 0) {                         // issue next half's loads now (T14)
            const int th = t0 + 32;
            rB = *(const ushort4*)(zxbc + (size_t)(th + btl) * ZXBC_N + OFF_B + xb0 + (bf_ << 2));
            #pragma unroll
            for (int k = 0; k < 4; ++k) {
                const int row = crow + (k << 3);
                rC[k] = *(const us8*)(zxbc + (size_t)(th + row) * ZXBC_N + OFF_C + c0 + (cgrp << 3));
            }
        }
        const int tb = t0 + (hh << 5);
        #pragma unroll 4
        for (int tl = 0; tl < 32; ++tl) {
            const int t = tb + tl;
            float dn = 0.f, xn = 0.f, zn = 0.f;
            if (t < t0 + TC - 1) {
                const size_t t1 = (size_t)(t + 1);
                dn = delta[t1 * DINNER + c];
                xn = bf2f(zxbc[t1 * ZXBC_N + OFF_X + xcol]);
                zn = bf2f(zxbc[t1 * ZXBC_N + OFF_Z + c]);
            }
            float Bv[16], Cv[16];
            *(float4*)(Bv +  0) = *(const float4*)&sB[tl][(xhl << 4) +  0];
            *(float4*)(Bv +  4) = *(const float4*)&sB[tl][(xhl << 4) +  4];
            *(float4*)(Bv +  8) = *(const float4*)&sB[tl][(xhl << 4) +  8];
            *(float4*)(Bv + 12) = *(const float4*)&sB[tl][(xhl << 4) + 12];
            *(float4*)(Cv +  0) = *(const float4*)&sC[tl][(gl << 4) +  0];
            *(float4*)(Cv +  4) = *(const float4*)&sC[tl][(gl << 4) +  4];
            *(float4*)(Cv +  8) = *(const float4*)&sC[tl][(gl << 4) +  8];
            *(float4*)(Cv + 12) = *(const float4*)&sC[tl][(gl << 4) + 12];
            float u = cb;
            u = fmaf(w4.x, xm3, u); u = fmaf(w4.y, xm2, u);
            u = fmaf(w4.z, xm1, u); u = fmaf(w4.w, xcur, u);
            u = silu_f(u);
            xm3 = xm2; xm2 = xm1; xm1 = xcur;
            const float du = dcur * u;
            float y0 = 0.f, y1 = 0.f, y2 = 0.f, y3 = 0.f;
            #pragma unroll
            for (int q = 0; q < 4; ++q) {
                const float dA0 = __expf(dcur * Av[q*4+0]);
                const float dA1 = __expf(dcur * Av[q*4+1]);
                const float dA2 = __expf(dcur * Av[q*4+2]);
                const float dA3 = __expf(dcur * Av[q*4+3]);
                h[q*4+0] = fmaf(h[q*4+0], dA0, du * Bv[q*4+0]);
                h[q*4+1] = fmaf(h[q*4+1], dA1, du * Bv[q*4+1]);
                h[q*4+2] = fmaf(h[q*4+2], dA2, du * Bv[q*4+2]);
                h[q*4+3] = fmaf(h[q*4+3], dA3, du * Bv[q*4+3]);
                y0 = fmaf(h[q*4+0], Cv[q*4+0], y0);
                y1 = fmaf(h[q*4+1], Cv[q*4+1], y1);
                y2 = fmaf(h[q*4+2], Cv[q*4+2], y2);
                y3 = fmaf(h[q*4+3], Cv[q*4+3], y3);
            }
            const float y = (y0 + y1) + (y2 + y3);
            const float yv = fmaf(u, Dv, y) * silu_f(zcur);
            ypre[(size_t)t * DINNER + c] = f2bf(yv);
            dcur = dn; xcur = xn; zcur = zn;
        }
    }
}

extern "C" void kernel_launch(void* const* d_in, const int* in_sizes, int n_in,
                              void* d_out, int out_size, void* d_ws, size_t ws_size,
                              hipStream_t stream) {
    const float* hidden       = (const float*)d_in[0];
    const float* in_proj_w    = (const float*)d_in[1];
    const float* dt_in_proj_w = (const float*)d_in[2];
    const float* dt_proj_w    = (const float*)d_in[3];
    const float* dt_proj_b    = (const float*)d_in[4];
    const float* conv_w       = (const float*)d_in[5];
    const float* conv_b       = (const float*)d_in[6];
    const float* A_log        = (const float*)d_in[7];
    const float* Dvec         = (const float*)d_in[8];
    const float* out_proj_w   = (const float*)d_in[9];

    // workspace layout (bytes) — same envelope as rounds 3-5 (~174MB peak).
    // zxbc region now bf16 (37.7MB used of 75.5MB); its tail/region is reused
    // after scan_pass2 for the out-proj split-K partials (33.6MB f32).
    char* wsb = (char*)d_ws;
    ushort* zxbc  = (ushort*)(wsb + 0ull);            // 37,748,736 (bf16)
    float*  opart = (float*) (wsb + 0ull);            // 33,554,432 (after pass2)
    float*  delta = (float*) (wsb + 75497472ull);     // 33,554,432
    ushort* ypre  = (ushort*)(wsb + 109051904ull);    // 16,777,216
    float*  t1part= (float*) (wsb + 109051904ull);    //  8,388,608 (dead before pass2)
    ushort* hb    = (ushort*)(wsb + 125829120ull);    //  8,388,608
    ushort* t1b   = (ushort*)(wsb + 134217728ull);    //    524,288
    ushort* wdtib = (ushort*)(wsb + 134742016ull);    //    524,288
    ushort* wdtpb = (ushort*)(wsb + 135266304ull);    //  1,048,576
    ushort* wbig  = (ushort*)(wsb + 136314880ull);    // 37,748,736 -> end 174,063,616
    float*  hend  = (float*) (wsb + 153092096ull);    //  8,388,608 (overlaps wbig tail)
    float*  dsum  = (float*) (wsb + 161480704ull);    //    524,288

    // fused converts: hidden, in_proj, dt_in_proj, dt_proj
    cvt4_kernel<<<23296, 256, 0, stream>>>(hidden, hb, in_proj_w, wbig,
                                           dt_in_proj_w, wdtib, dt_proj_w, wdtpb);

    // zxbc = hidden @ in_proj_w^T  (bf16 out)
    gemm_bt_bf16<2><<<1152, 256, 0, stream>>>(hb, wbig, zxbc, nullptr, SEQ, ZXBC_N, DMODEL);
    // wbig now free -> out_proj bf16 (first 16.8MB of wbig)
    f32_to_bf16<<<8192, 256, 0, stream>>>(out_proj_w, wbig, 2097152);
    // t1 = hidden @ dt_in_proj_w^T : split-K x8 partials then reduce -> bf16
    gemm_bt_bf16<0><<<dim3(16, 8), 256, 0, stream>>>(hb, wdtib, t1part, nullptr, SEQ, DTRANK, 256);
    t1_reduce<<<256, 256, 0, stream>>>(t1part, t1b);
    // delta = softplus(t1 @ dt_proj_w^T + dt_proj_b)  (f32 out)
    gemm_bt_bf16<1><<<512, 256, 0, stream>>>(t1b, wdtpb, delta, dt_proj_b, SEQ, DINNER, DTRANK);

    // chunked scan (thread = channel)
    scan_pass1<<<dim3(16, NCH), 256, 0, stream>>>(zxbc, delta, conv_w, conv_b, A_log, hend, dsum);
    scan_mid  <<<256, 256, 0, stream>>>(A_log, hend, dsum);
    scan_pass2<<<dim3(16, NCH), 256, 0, stream>>>(zxbc, delta, conv_w, conv_b, A_log, Dvec, hend, ypre);

    // out = ypre @ out_proj_w^T : split-K x2 (zxbc region now dead) + reduce
    gemm_bt_bf16<0><<<dim3(256, 2), 256, 0, stream>>>(ypre, wbig, opart, nullptr, SEQ, DMODEL, 2048);
    out_reduce2<<<4096, 256, 0, stream>>>(opart, (float*)d_out);
}